// Round 17
// baseline (720.877 us; speedup 1.0000x reference)
//
#include <hip/hip_runtime.h>
#include <hip/hip_bf16.h>
#include <math.h>

using bf16 = __hip_bfloat16;
typedef __attribute__((ext_vector_type(8))) short bf16x8;
typedef __attribute__((ext_vector_type(4))) float f32x4;

#define DEVI __device__ __forceinline__

DEVI float b2f(bf16 v) { return __bfloat162float(v); }
DEVI bf16 f2b(float v) { return __float2bfloat16(v); }
DEVI short b2s(bf16 v) { return *reinterpret_cast<short*>(&v); }
DEVI float s2f(short s) {
  unsigned int u = ((unsigned int)(unsigned short)s) << 16;
  return __uint_as_float(u);
}
DEVI float geluf(float x) { return 0.5f * x * (1.0f + erff(x * 0.70710678118654752f)); }
DEVI float fsilu(float x) { return x / (1.0f + __expf(-x)); }  // fast-exp silu (err ~1e-6)

DEVI void load_lds16(const bf16* g, bf16* l) {
  __builtin_amdgcn_global_load_lds(
      (const __attribute__((address_space(1))) void*)g,
      (__attribute__((address_space(3))) void*)l, 16, 0, 0);
}

// ---------------- prep kernels ----------------
__global__ __launch_bounds__(256) void cast_kernel(const float* __restrict__ in,
                                                   bf16* __restrict__ out, int n4) {
  int i = blockIdx.x * 256 + threadIdx.x;
  if (i >= n4) return;
  float4 v = reinterpret_cast<const float4*>(in)[i];
  bf16 o[4] = { f2b(v.x), f2b(v.y), f2b(v.z), f2b(v.w) };
  reinterpret_cast<uint2*>(out)[i] = *reinterpret_cast<uint2*>(o);
}

// combined cast: w_qkv (6144x1024) then w_beta rows' first 1024 cols (stride 2048)
// into one contiguous bf16 B operand [8192][1024].
__global__ __launch_bounds__(256) void castqb_kernel(const float* __restrict__ wq,
                                                     const float* __restrict__ wb,
                                                     bf16* __restrict__ out) {
  long g = (long)blockIdx.x * 256 + threadIdx.x;  // f32x4 units, 2097152 total
  if (g < 1572864) {
    float4 v = reinterpret_cast<const float4*>(wq)[g];
    bf16 o[4] = { f2b(v.x), f2b(v.y), f2b(v.z), f2b(v.w) };
    reinterpret_cast<uint2*>(out)[g] = *reinterpret_cast<uint2*>(o);
  } else {
    long gb = g - 1572864;        // 524288 vec4
    long eb = gb >> 8;            // beta row (256 vec4 per 1024-col row)
    long jb = (gb & 255) * 4;
    float4 v = *reinterpret_cast<const float4*>(&wb[eb * 2048 + jb]);
    bf16 o[4] = { f2b(v.x), f2b(v.y), f2b(v.z), f2b(v.w) };
    *reinterpret_cast<uint2*>(&out[6291456 + eb * 1024 + jb]) = *reinterpret_cast<uint2*>(o);
  }
}

// merged pmean (0-3) + wb2sum (4-515) + convw pack (516-523).
// Pack-in-prep is safe now: no wbuf cast exceeds 8.4MB < wpl offset 11.5MB.
__global__ __launch_bounds__(256) void prep_kernel(const float* __restrict__ rel,
                                                   float* __restrict__ pm,
                                                   const float* __restrict__ wb,
                                                   float* __restrict__ wb2s,
                                                   const float* __restrict__ cw,
                                                   bf16* __restrict__ wpl) {
  const int b = blockIdx.x;
  if (b < 4) {
    int h = b * 256 + threadIdx.x;
    float s = 0.f;
    for (int m = 0; m < 1024; ++m) s += rel[m * 1024 + h];
    pm[h] = s * (1.0f / 1024.0f);
  } else if (b < 516) {
    int e = (b - 4) * 4 + (threadIdx.x >> 6);
    int lane = threadIdx.x & 63;
    float s = 0.f;
    for (int j = lane; j < 1024; j += 64) s += wb[(long)e * 2048 + 1024 + j];
#pragma unroll
    for (int off = 32; off > 0; off >>= 1) s += __shfl_down(s, off);
    if (lane == 0) wb2s[e] = s;
  } else {
    int e = (b - 516) * 256 + threadIdx.x;  // 2048
    wpl[e]        = f2b(cw[e * 3]);
    wpl[2048 + e] = f2b(cw[e * 3 + 1]);
    wpl[4096 + e] = f2b(cw[e * 3 + 2]);
  }
}

// ---------------- LayerNorm kernels ----------------
template<bool POS>
__global__ __launch_bounds__(256) void ln1024_kernel(
    const float* __restrict__ x, const float* __restrict__ w, const float* __restrict__ b,
    bf16* __restrict__ out, const float* __restrict__ pmean, float* __restrict__ pos) {
  __shared__ float red[12];
  long row = blockIdx.x;
  int t = threadIdx.x, lane = t & 63, wid = t >> 6;
  float4 xv = reinterpret_cast<const float4*>(x + row * 1024)[t];
  float s = xv.x + xv.y + xv.z + xv.w;
  float ss = xv.x * xv.x + xv.y * xv.y + xv.z * xv.z + xv.w * xv.w;
#pragma unroll
  for (int off = 32; off > 0; off >>= 1) { s += __shfl_down(s, off); ss += __shfl_down(ss, off); }
  if (lane == 0) { red[wid] = s; red[4 + wid] = ss; }
  __syncthreads();
  s = red[0] + red[1] + red[2] + red[3];
  ss = red[4] + red[5] + red[6] + red[7];
  float mean = s * (1.0f / 1024.0f);
  float rstd = rsqrtf(ss * (1.0f / 1024.0f) - mean * mean + 1e-5f);
  float4 wv = reinterpret_cast<const float4*>(w)[t];
  float4 bv = reinterpret_cast<const float4*>(b)[t];
  float h0 = (xv.x - mean) * rstd * wv.x + bv.x;
  float h1 = (xv.y - mean) * rstd * wv.y + bv.y;
  float h2 = (xv.z - mean) * rstd * wv.z + bv.z;
  float h3 = (xv.w - mean) * rstd * wv.w + bv.w;
  bf16 o[4] = { f2b(h0), f2b(h1), f2b(h2), f2b(h3) };
  reinterpret_cast<uint2*>(out + row * 1024)[t] = *reinterpret_cast<uint2*>(o);
  if (POS) {
    float4 pv = reinterpret_cast<const float4*>(pmean)[t];
    float d = h0 * pv.x + h1 * pv.y + h2 * pv.z + h3 * pv.w;
#pragma unroll
    for (int off = 32; off > 0; off >>= 1) d += __shfl_down(d, off);
    if (lane == 0) red[8 + wid] = d;
    __syncthreads();
    if (t == 0) pos[row] = red[8] + red[9] + red[10] + red[11];
  }
}

// bf16-input variant (for h2 = LN(x2b))
__global__ __launch_bounds__(256) void ln1024b_kernel(
    const bf16* __restrict__ x, const float* __restrict__ w, const float* __restrict__ b,
    bf16* __restrict__ out) {
  __shared__ float red[8];
  long row = blockIdx.x;
  int t = threadIdx.x, lane = t & 63, wid = t >> 6;
  bf16 tv[4];
  *reinterpret_cast<uint2*>(tv) = reinterpret_cast<const uint2*>(x + row * 1024)[t];
  float v[4], s = 0.f, ss = 0.f;
#pragma unroll
  for (int j = 0; j < 4; ++j) { v[j] = b2f(tv[j]); s += v[j]; ss += v[j] * v[j]; }
#pragma unroll
  for (int off = 32; off > 0; off >>= 1) { s += __shfl_down(s, off); ss += __shfl_down(ss, off); }
  if (lane == 0) { red[wid] = s; red[4 + wid] = ss; }
  __syncthreads();
  s = red[0] + red[1] + red[2] + red[3];
  ss = red[4] + red[5] + red[6] + red[7];
  float mean = s * (1.0f / 1024.0f);
  float rstd = rsqrtf(ss * (1.0f / 1024.0f) - mean * mean + 1e-5f);
  float4 wv = reinterpret_cast<const float4*>(w)[t];
  float4 bv = reinterpret_cast<const float4*>(b)[t];
  bf16 o[4];
  o[0] = f2b((v[0] - mean) * rstd * wv.x + bv.x);
  o[1] = f2b((v[1] - mean) * rstd * wv.y + bv.y);
  o[2] = f2b((v[2] - mean) * rstd * wv.z + bv.z);
  o[3] = f2b((v[3] - mean) * rstd * wv.w + bv.w);
  reinterpret_cast<uint2*>(out + row * 1024)[t] = *reinterpret_cast<uint2*>(o);
}

__global__ __launch_bounds__(256) void ln2048_bf16_kernel(
    const bf16* __restrict__ in, const float* __restrict__ w, const float* __restrict__ b,
    bf16* __restrict__ out) {
  __shared__ float red[8];
  long row = blockIdx.x;
  int t = threadIdx.x, lane = t & 63, wid = t >> 6;
  bf16 tv[8];
  *reinterpret_cast<int4*>(tv) = reinterpret_cast<const int4*>(in + row * 2048)[t];
  float v[8], s = 0.f, ss = 0.f;
#pragma unroll
  for (int j = 0; j < 8; ++j) { v[j] = b2f(tv[j]); s += v[j]; ss += v[j] * v[j]; }
#pragma unroll
  for (int off = 32; off > 0; off >>= 1) { s += __shfl_down(s, off); ss += __shfl_down(ss, off); }
  if (lane == 0) { red[wid] = s; red[4 + wid] = ss; }
  __syncthreads();
  s = red[0] + red[1] + red[2] + red[3];
  ss = red[4] + red[5] + red[6] + red[7];
  float mean = s * (1.0f / 2048.0f);
  float rstd = rsqrtf(ss * (1.0f / 2048.0f) - mean * mean + 1e-5f);
  int base = t * 8;
  bf16 o[8];
#pragma unroll
  for (int j = 0; j < 8; ++j) o[j] = f2b((v[j] - mean) * rstd * w[base + j] + b[base + j]);
  reinterpret_cast<int4*>(out + row * 2048)[t] = *reinterpret_cast<int4*>(o);
}

// ======= tiled fused act/cross-norm + dwconv for q,k (round-12 proven) =======
#define QK_TAP(RR, WV) { \
  float qmv = s2f(qs[RR][j]), kmv = s2f(ks[RR][j]); \
  float qn = qmv * rq[RR] + 0.1f * kmv; \
  float kn = kmv * rk[RR] + 0.1f * qn; \
  accq += b2f(WV[j]) * b2f(f2b(qn)); \
  acck += b2f(WV[j]) * b2f(f2b(kn)); }

__global__ __launch_bounds__(256) void actconv_qk_kernel(
    const bf16* __restrict__ qraw, const bf16* __restrict__ kraw,
    bf16* __restrict__ qout, bf16* __restrict__ kout, const bf16* __restrict__ wpl) {
  __shared__ float red[10][2][4];
  const int t = threadIdx.x, lane = t & 63, wid = t >> 6;
  const int e0 = t * 8;
  const int bb = blockIdx.x >> 7;
  const int l0 = (blockIdx.x & 127) * 8;
  const long rowbase = (long)bb * 1024 * 2048;
  bf16x8 qs[10], ks[10];
#pragma unroll
  for (int r = 0; r < 10; ++r) {
    int dl = l0 + r - 1;
    float sq = 0.f, sk = 0.f;
    if (dl >= 0 && dl < 1024) {
      long off = rowbase + (long)dl * 2048 + e0;
      bf16 tq[8], tk[8];
      *reinterpret_cast<int4*>(tq) = *reinterpret_cast<const int4*>(qraw + off);
      *reinterpret_cast<int4*>(tk) = *reinterpret_cast<const int4*>(kraw + off);
#pragma unroll
      for (int j = 0; j < 8; ++j) {
        float qv = fsilu(b2f(tq[j])); sq += qv * qv; qs[r][j] = b2s(f2b(qv));
        float kv = fsilu(b2f(tk[j])); sk += kv * kv; ks[r][j] = b2s(f2b(kv));
      }
    } else {
      qs[r] = 0; ks[r] = 0;
    }
#pragma unroll
    for (int off = 32; off > 0; off >>= 1) { sq += __shfl_down(sq, off); sk += __shfl_down(sk, off); }
    if (lane == 0) { red[r][0][wid] = sq; red[r][1][wid] = sk; }
  }
  __syncthreads();
  float rq[10], rk[10];
#pragma unroll
  for (int r = 0; r < 10; ++r) {
    float sq = red[r][0][0] + red[r][0][1] + red[r][0][2] + red[r][0][3];
    float sk = red[r][1][0] + red[r][1][1] + red[r][1][2] + red[r][1][3];
    rq[r] = 1.0f / fmaxf(sqrtf(sq), 1e-12f);
    rk[r] = 1.0f / fmaxf(sqrtf(sk), 1e-12f);
  }
  bf16 w0[8], w1[8], w2[8];
  *reinterpret_cast<int4*>(w0) = *reinterpret_cast<const int4*>(wpl + e0);
  *reinterpret_cast<int4*>(w1) = *reinterpret_cast<const int4*>(wpl + 2048 + e0);
  *reinterpret_cast<int4*>(w2) = *reinterpret_cast<const int4*>(wpl + 4096 + e0);
#pragma unroll
  for (int rr = 1; rr <= 8; ++rr) {
    const int l = l0 + rr - 1;
    bf16 oq[8], ok[8];
#pragma unroll
    for (int j = 0; j < 8; ++j) {
      float accq = 0.f, acck = 0.f;
      QK_TAP(rr, w1);
      if (l > 0)    QK_TAP(rr - 1, w0);
      if (l < 1023) QK_TAP(rr + 1, w2);
      oq[j] = f2b(accq); ok[j] = f2b(acck);
    }
    long off = rowbase + (long)l * 2048 + e0;
    *reinterpret_cast<int4*>(qout + off) = *reinterpret_cast<int4*>(oq);
    *reinterpret_cast<int4*>(kout + off) = *reinterpret_cast<int4*>(ok);
  }
}

// ======= fused v-path: gelu + dwconv + beta-mult + transpose (round-16 proven) =======
__global__ __launch_bounds__(256) void transpose_vb_kernel(
    const bf16* __restrict__ vraw, const bf16* __restrict__ beta,
    bf16* __restrict__ vt, const bf16* __restrict__ wpl) {
  const long base = (long)blockIdx.z * 2097152;
  const int r0 = blockIdx.y * 64 + ((threadIdx.x & 63) >> 3) * 8;
  const int c0 = blockIdx.x * 256 + (threadIdx.x >> 6) * 64 + (threadIdx.x & 7) * 8;
  bf16 g[10][8];
#pragma unroll
  for (int j = 0; j < 10; ++j) {
    int r = r0 + j - 1;
    if (r >= 0 && r < 1024) {
      bf16 raw[8];
      *reinterpret_cast<int4*>(raw) =
          *reinterpret_cast<const int4*>(&vraw[base + (long)r * 2048 + c0]);
#pragma unroll
      for (int i = 0; i < 8; ++i) g[j][i] = f2b(geluf(b2f(raw[i])));
    } else {
#pragma unroll
      for (int i = 0; i < 8; ++i) g[j][i] = f2b(0.f);
    }
  }
  bf16 w0[8], w1[8], w2[8];
  *reinterpret_cast<int4*>(w0) = *reinterpret_cast<const int4*>(&wpl[c0]);
  *reinterpret_cast<int4*>(w1) = *reinterpret_cast<const int4*>(&wpl[2048 + c0]);
  *reinterpret_cast<int4*>(w2) = *reinterpret_cast<const int4*>(&wpl[4096 + c0]);
  bf16 vv[8][8];
#pragma unroll
  for (int j = 0; j < 8; ++j) {
    const int l = r0 + j;
    bf16 bt[8];
    *reinterpret_cast<int4*>(bt) =
        *reinterpret_cast<const int4*>(&beta[base + (long)l * 2048 + c0]);
#pragma unroll
    for (int i = 0; i < 8; ++i) {
      float a = b2f(w1[i]) * b2f(g[j + 1][i]);
      if (l > 0)    a += b2f(w0[i]) * b2f(g[j][i]);
      if (l < 1023) a += b2f(w2[i]) * b2f(g[j + 2][i]);
      vv[j][i] = f2b(b2f(bt[i]) * a);
    }
  }
#pragma unroll
  for (int i = 0; i < 8; ++i) {
    bf16 w[8];
#pragma unroll
    for (int j = 0; j < 8; ++j) w[j] = vv[j][i];
    *reinterpret_cast<int4*>(&vt[base + (long)(c0 + i) * 1024 + r0]) =
        *reinterpret_cast<int4*>(w);
  }
}

enum { EPI_QKVB = 0, EPI_SCALE = 1, EPI_GELU = 2 };

// ================= 256x256 8-phase NT GEMM (round-5/12 proven schedule) =================
// NOTE (round-13 lesson): do NOT hoist all fragment reads to phase top — spills.
#define MF(d, a, b) d = __builtin_amdgcn_mfma_f32_16x16x32_bf16(a, b, d, 0, 0, 0)
#define RD_A(S, MR, KK) \
  (*reinterpret_cast<const bf16x8*>(&smem[(S)*16384 + wm*8192 + ((MR)*16 + r16)*64 + ((((KK)*32) + kq8) ^ swz)]))
#define RD_B(S, NR, KK) \
  (*reinterpret_cast<const bf16x8*>(&smem[32768 + (S)*16384 + (wn>>1)*8192 + ((wn&1)*64 + (NR)*16 + r16)*64 + ((((KK)*32) + kq8) ^ swz)]))
#define STAGE_A1(S, H, Q, KT) \
  load_lds16(Abase + (long)((H)*128 + (Q)*64) * lda + (long)(KT)*64, \
             &smem[(S)*16384 + (H)*8192 + (Q)*4096 + wid*512])
#define STAGE_B1(S, H, Q, KT) \
  load_lds16(Bbase + (long)((H)*128 + (Q)*64) * ldb + (long)(KT)*64, \
             &smem[32768 + (S)*16384 + (H)*8192 + (Q)*4096 + wid*512])
#define STAGE_AH(S, H, KT) { STAGE_A1(S, H, 0, KT); STAGE_A1(S, H, 1, KT); }
#define STAGE_BH(S, H, KT) { STAGE_B1(S, H, 0, KT); STAGE_B1(S, H, 1, KT); }
#define BAR_A __builtin_amdgcn_s_barrier()
#define LGKM0 { asm volatile("s_waitcnt lgkmcnt(0)" ::: "memory"); __builtin_amdgcn_sched_barrier(0); }
#define VWAIT(LST) { if (LST) { asm volatile("s_waitcnt vmcnt(0)" ::: "memory"); } \
                     else     { asm volatile("s_waitcnt vmcnt(6)" ::: "memory"); } \
                     __builtin_amdgcn_sched_barrier(0); }

#define KTILE(S, ST1, ST2, ST3, ST4, W4) { \
  bf16x8 aL[4][2], aH[4][2], bL[2][2], bH[2][2]; \
  _Pragma("unroll") for (int m_ = 0; m_ < 4; ++m_) { aL[m_][0] = RD_A(S, m_, 0); aL[m_][1] = RD_A(S, m_, 1); } \
  _Pragma("unroll") for (int n_ = 0; n_ < 2; ++n_) { bL[n_][0] = RD_B(S, n_, 0); bL[n_][1] = RD_B(S, n_, 1); } \
  ST1; BAR_A; LGKM0; \
  __builtin_amdgcn_s_setprio(1); \
  _Pragma("unroll") for (int m_ = 0; m_ < 4; ++m_) _Pragma("unroll") for (int n_ = 0; n_ < 2; ++n_) { \
    MF(acc[m_][n_], aL[m_][0], bL[n_][0]); MF(acc[m_][n_], aL[m_][1], bL[n_][1]); } \
  __builtin_amdgcn_s_setprio(0); __builtin_amdgcn_s_barrier(); \
  _Pragma("unroll") for (int n_ = 0; n_ < 2; ++n_) { bH[n_][0] = RD_B(S, n_ + 2, 0); bH[n_][1] = RD_B(S, n_ + 2, 1); } \
  ST2; BAR_A; LGKM0; \
  __builtin_amdgcn_s_setprio(1); \
  _Pragma("unroll") for (int m_ = 0; m_ < 4; ++m_) _Pragma("unroll") for (int n_ = 0; n_ < 2; ++n_) { \
    MF(acc[m_][n_ + 2], aL[m_][0], bH[n_][0]); MF(acc[m_][n_ + 2], aL[m_][1], bH[n_][1]); } \
  __builtin_amdgcn_s_setprio(0); __builtin_amdgcn_s_barrier(); \
  _Pragma("unroll") for (int m_ = 0; m_ < 4; ++m_) { aH[m_][0] = RD_A(S, m_ + 4, 0); aH[m_][1] = RD_A(S, m_ + 4, 1); } \
  ST3; BAR_A; LGKM0; \
  __builtin_amdgcn_s_setprio(1); \
  _Pragma("unroll") for (int m_ = 0; m_ < 4; ++m_) _Pragma("unroll") for (int n_ = 0; n_ < 2; ++n_) { \
    MF(acc[m_ + 4][n_], aH[m_][0], bL[n_][0]); MF(acc[m_ + 4][n_], aH[m_][1], bL[n_][1]); } \
  __builtin_amdgcn_s_setprio(0); __builtin_amdgcn_s_barrier(); \
  ST4; W4; BAR_A; LGKM0; \
  __builtin_amdgcn_s_setprio(1); \
  _Pragma("unroll") for (int m_ = 0; m_ < 4; ++m_) _Pragma("unroll") for (int n_ = 0; n_ < 2; ++n_) { \
    MF(acc[m_ + 4][n_ + 2], aH[m_][0], bH[n_][0]); MF(acc[m_ + 4][n_ + 2], aH[m_][1], bH[n_][1]); } \
  __builtin_amdgcn_s_setprio(0); __builtin_amdgcn_s_barrier(); \
}

template<int EPI>
__global__ __launch_bounds__(512) void gemm256_kernel(
    const bf16* __restrict__ A, int lda, long sA,
    const bf16* __restrict__ B, int ldb, long sB,
    void* __restrict__ Cv, int ldc, long sC, int K,
    const float* __restrict__ bias, const float* __restrict__ aux_row,
    const float* __restrict__ aux_col, const float* __restrict__ bias2,
    const float* __restrict__ scale_ptr,
    bf16* __restrict__ p2, bf16* __restrict__ p3, bf16* __restrict__ p4) {
  __shared__ bf16 smem[65536];
  const int bz = blockIdx.z;
  A += (long)bz * sA;
  B += (long)bz * sB;
  const int m0 = blockIdx.y * 256, n0 = blockIdx.x * 256;
  const int t = threadIdx.x, lane = t & 63, wid = t >> 6;
  const int wm = wid >> 2, wn = wid & 3;
  const int r16 = lane & 15, kq8 = (lane >> 4) * 8;
  const int swz = (r16 & 7) << 3;
  const int lrow = lane >> 3;
  const int cswz = ((lane & 7) ^ lrow) * 8;
  const bf16* Abase = A + (long)(m0 + wid * 8 + lrow) * lda + cswz;
  const bf16* Bbase = B + (long)(n0 + wid * 8 + lrow) * ldb + cswz;
  f32x4 acc[8][4] = {};
  const int NT = K >> 6, NIT = NT >> 1;
  STAGE_AH(0, 0, 0); STAGE_AH(0, 1, 0); STAGE_BH(0, 0, 0); STAGE_BH(0, 1, 0);
  STAGE_BH(1, 0, 1); STAGE_BH(1, 1, 1); STAGE_AH(1, 0, 1);
  asm volatile("s_waitcnt vmcnt(6)" ::: "memory");
  __builtin_amdgcn_sched_barrier(0);
  __builtin_amdgcn_s_barrier();
  for (int i = 0; i < NIT; ++i) {
    const int tb = 2 * i;
    const bool lst = (i == NIT - 1);
    KTILE(0,
      { STAGE_AH(1, 1, tb + 1); },
      { },
      { if (!lst) { STAGE_BH(0, 0, tb + 2); STAGE_BH(0, 1, tb + 2); } },
      { if (!lst) { STAGE_AH(0, 0, tb + 2); } },
      VWAIT(lst));
    KTILE(1,
      { if (!lst) { STAGE_AH(0, 1, tb + 2); } },
      { },
      { if (!lst) { STAGE_BH(1, 0, tb + 3); STAGE_BH(1, 1, tb + 3); } },
      { if (!lst) { STAGE_AH(1, 0, tb + 3); } },
      VWAIT(lst));
  }
  float scl = 1.0f;
  if (EPI == EPI_SCALE) scl = scale_ptr[0];
  const int rb = (lane >> 4) * 4;
#pragma unroll
  for (int mr = 0; mr < 8; ++mr) {
#pragma unroll
    for (int nr = 0; nr < 4; ++nr) {
#pragma unroll
      for (int r = 0; r < 4; ++r) {
        const long gm = m0 + wm * 128 + mr * 16 + rb + r;
        const int gn = n0 + wn * 64 + nr * 16 + r16;
        const long idx = (long)bz * sC + gm * (long)ldc + gn;
        float v = acc[mr][nr][r];
        if (EPI == EPI_QKVB) {
          const int seg = gn >> 11, cc = gn & 2047;
          if (seg < 3) {
            bf16* dst = (seg == 0) ? (bf16*)Cv : (seg == 1) ? p2 : p3;
            dst[gm * 2048 + cc] = f2b(v + bias[gn]);
          } else {
            float tt = v + bias2[cc] + aux_row[gm] * aux_col[cc];
            float be = 0.9f / (1.0f + expf(-tt)) + 0.1f;
            p4[gm * 2048 + cc] = f2b(be);
          }
        } else if (EPI == EPI_SCALE) {
          ((bf16*)Cv)[idx] = f2b(v * scl);
        } else {
          ((bf16*)Cv)[idx] = f2b(geluf(v + bias[gn]));
        }
      }
    }
  }
}

// ================= 128x256-tile pipelined NT GEMM =================
// RB: resid bf16 (else f32). WB: out bf16 (else f32). NR: no bias/resid.
#define A_RD(S, MR, KK) \
  (*reinterpret_cast<const bf16x8*>(&amem[(S)*8192 + (wm*64 + (MR)*16 + r16)*64 + ((((KK)*32) + kq8) ^ swz)]))
#define B_RD(S, NR, KK) \
  (*reinterpret_cast<const bf16x8*>(&amem[16384 + (S)*16384 + (wn*64 + (NR)*16 + r16)*64 + ((((KK)*32) + kq8) ^ swz)]))
#define A_ST(S, Q, KT) \
  load_lds16(Abase + (long)((Q)*64) * lda + (long)(KT)*64, &amem[(S)*8192 + (Q)*4096 + wid*512])
#define B_ST(S, Q, KT) \
  load_lds16(Bbase + (long)((Q)*64) * ldb + (long)(KT)*64, &amem[16384 + (S)*16384 + (Q)*4096 + wid*512])
#define STAGE_T(S, KT) { A_ST(S, 0, KT); A_ST(S, 1, KT); B_ST(S, 0, KT); B_ST(S, 1, KT); B_ST(S, 2, KT); B_ST(S, 3, KT); }

template<int RB, int WB, int NR>
__global__ __launch_bounds__(512) void gemmA128_kernel(
    const bf16* __restrict__ A, int lda, long sA,
    const bf16* __restrict__ B, int ldb, long sB,
    void* __restrict__ Cv, int ldc, long sC, int K,
    const float* __restrict__ bias, const void* __restrict__ residv) {
  __shared__ bf16 amem[49152];
  A += (long)blockIdx.z * sA;
  B += (long)blockIdx.z * sB;
  const int m0 = blockIdx.y * 128, n0 = blockIdx.x * 256;
  const int t = threadIdx.x, lane = t & 63, wid = t >> 6;
  const int wm = wid >> 2, wn = wid & 3;
  const int r16 = lane & 15, kq8 = (lane >> 4) * 8;
  const int swz = (r16 & 7) << 3;
  const int lrow = lane >> 3;
  const int cswz = ((lane & 7) ^ lrow) * 8;
  const bf16* Abase = A + (long)(m0 + wid * 8 + lrow) * lda + cswz;
  const bf16* Bbase = B + (long)(n0 + wid * 8 + lrow) * ldb + cswz;
  f32x4 acc[4][4] = {};
  const int NT = K >> 6;
  STAGE_T(0, 0); STAGE_T(1, 1);
  asm volatile("s_waitcnt vmcnt(6)" ::: "memory");
  __builtin_amdgcn_sched_barrier(0);
  __builtin_amdgcn_s_barrier();
  for (int tt = 0; tt < NT; ++tt) {
    const int S = tt & 1;
    const bool pre = (tt + 2 < NT);
    bf16x8 a[4][2], bL[2][2], bH[2][2];
#pragma unroll
    for (int m_ = 0; m_ < 4; ++m_) { a[m_][0] = A_RD(S, m_, 0); a[m_][1] = A_RD(S, m_, 1); }
#pragma unroll
    for (int n_ = 0; n_ < 2; ++n_) { bL[n_][0] = B_RD(S, n_, 0); bL[n_][1] = B_RD(S, n_, 1); }
#pragma unroll
    for (int n_ = 0; n_ < 2; ++n_) { bH[n_][0] = B_RD(S, n_ + 2, 0); bH[n_][1] = B_RD(S, n_ + 2, 1); }
    LGKM0;
    __builtin_amdgcn_s_setprio(1);
#pragma unroll
    for (int m_ = 0; m_ < 4; ++m_)
#pragma unroll
      for (int n_ = 0; n_ < 2; ++n_) {
        MF(acc[m_][n_], a[m_][0], bL[n_][0]); MF(acc[m_][n_], a[m_][1], bL[n_][1]);
      }
    __builtin_amdgcn_s_setprio(0);
    __builtin_amdgcn_s_barrier();
    __builtin_amdgcn_sched_barrier(0);
    if (pre) STAGE_T(S, tt + 2);
    __builtin_amdgcn_s_setprio(1);
#pragma unroll
    for (int m_ = 0; m_ < 4; ++m_)
#pragma unroll
      for (int n_ = 0; n_ < 2; ++n_) {
        MF(acc[m_][n_ + 2], a[m_][0], bH[n_][0]); MF(acc[m_][n_ + 2], a[m_][1], bH[n_][1]);
      }
    __builtin_amdgcn_s_setprio(0);
    if (pre) { asm volatile("s_waitcnt vmcnt(6)" ::: "memory"); }
    else     { asm volatile("s_waitcnt vmcnt(0)" ::: "memory"); }
    __builtin_amdgcn_sched_barrier(0);
    __builtin_amdgcn_s_barrier();
    __builtin_amdgcn_sched_barrier(0);
  }
  const int rb = (lane >> 4) * 4;
#pragma unroll
  for (int mr = 0; mr < 4; ++mr) {
#pragma unroll
    for (int nr = 0; nr < 4; ++nr) {
#pragma unroll
      for (int r = 0; r < 4; ++r) {
        const long gm = m0 + wm * 64 + mr * 16 + rb + r;
        const int gn = n0 + wn * 64 + nr * 16 + r16;
        const long idx = (long)blockIdx.z * sC + gm * (long)ldc + gn;
        float o = acc[mr][nr][r];
        if (!NR) {
          o += bias[gn];
          o += RB ? b2f(((const bf16*)residv)[idx]) : ((const float*)residv)[idx];
        }
        if (WB) ((bf16*)Cv)[idx] = f2b(o);
        else    ((float*)Cv)[idx] = o;
      }
    }
  }
}

// ---------------- orchestration ----------------
extern "C" void kernel_launch(void* const* d_in, const int* in_sizes, int n_in,
                              void* d_out, int out_size, void* d_ws, size_t ws_size,
                              hipStream_t stream) {
  (void)in_sizes; (void)n_in; (void)out_size;
  const float* x       = (const float*)d_in[0];
  const float* ln1_w   = (const float*)d_in[1];
  const float* ln1_b   = (const float*)d_in[2];
  const float* ln2_w   = (const float*)d_in[3];
  const float* ln2_b   = (const float*)d_in[4];
  const float* w_qkv   = (const float*)d_in[5];
  const float* b_qkv   = (const float*)d_in[6];
  const float* w_out   = (const float*)d_in[7];
  const float* b_out   = (const float*)d_in[8];
  const float* rel_pos = (const float*)d_in[9];
  const float* w_beta  = (const float*)d_in[10];
  const float* b_beta  = (const float*)d_in[11];
  const float* w1      = (const float*)d_in[12];
  const float* b1      = (const float*)d_in[13];
  const float* w2      = (const float*)d_in[14];
  const float* b2      = (const float*)d_in[15];
  const float* conv_w  = (const float*)d_in[16];
  const float* attn_sc = (const float*)d_in[17];
  float* out = (float*)d_out;

  if (ws_size < 180400128UL) return;
  char* ws = (char*)d_ws;
  bf16*  wbuf    = (bf16*)(ws + 0);            // w_out/w1/w2 casts (max 8.4MB)
  bf16*  wpl     = (bf16*)(ws + 11534336UL);   // conv planes; safe: no cast >= 11.5MB now
  float* pmean   = (float*)(ws + 12582912UL);
  float* wb2s    = (float*)(ws + 12587008UL);
  float* posinfo = (float*)(ws + 12595200UL);
  bf16* R0 = (bf16*)(ws + 12627968UL);   // h -> v_t -> out_ln
  bf16* R1 = (bf16*)(ws + 46182400UL);   // q_raw -> x2b
  bf16* R2 = (bf16*)(ws + 79736832UL);   // k_raw -> scores -> h2
  bf16* R3 = (bf16*)(ws + 113291264UL);  // beta -> k_conv -> attn -> m1(lo)
  bf16* R4 = (bf16*)(ws + 146845696UL);  // wqkv+wbeta bf16 (16.8MB) -> q_conv -> m1(hi)
  bf16* vscr = (bf16*)d_out;             // v_raw scratch (dead before final write)
  bf16* x2b = R1;

  // prep: pmean + wb2sum + conv-plane pack (one launch)
  prep_kernel<<<524, 256, 0, stream>>>(rel_pos, pmean, w_beta, wb2s, conv_w, wpl);

  ln1024_kernel<true><<<8192, 256, 0, stream>>>(x, ln1_w, ln1_b, R0, pmean, posinfo);

  // merged weights: [w_qkv (6144x1024); w_beta[:, :1024] (2048x1024)] -> R4
  castqb_kernel<<<8192, 256, 0, stream>>>(w_qkv, w_beta, R4);

  // merged qkv+beta GEMM: q->R1, k->R2, v->vscr, beta->R3
  gemm256_kernel<EPI_QKVB><<<dim3(32, 32, 1), 512, 0, stream>>>(
      R0, 1024, 0, R4, 1024, 0, R1, 2048, 0, 1024,
      b_qkv, posinfo, wb2s, b_beta, nullptr, R2, vscr, R3);

  // fused v-path: v_t = T(beta * conv(gelu(v_raw))) -> R0 (h dead)
  transpose_vb_kernel<<<dim3(8, 16, 8), 256, 0, stream>>>(vscr, R3, R0, wpl);

  // fused act+norm+conv: q_conv->R4 (weights dead), k_conv->R3 (beta dead)
  actconv_qk_kernel<<<1024, 256, 0, stream>>>(R1, R2, R4, R3, wpl);

  // scores[l,l'] = sum_e q_conv[l,e] k_conv[l',e] -> R2 (k_raw dead)
  gemmA128_kernel<0, 1, 1><<<dim3(4, 8, 8), 512, 0, stream>>>(
      R4, 2048, 2097152, R3, 2048, 2097152, R2, 1024, 1048576, 2048,
      nullptr, nullptr);

  // attn[l,f] = (sum_l' scores[l,l'] v_t[f,l']) * scale -> R3 (k_conv dead)
  gemm256_kernel<EPI_SCALE><<<dim3(8, 4, 8), 512, 0, stream>>>(
      R2, 1024, 1048576, R0, 1024, 2097152, R3, 2048, 2097152, 1024,
      nullptr, nullptr, nullptr, nullptr, attn_sc, nullptr, nullptr, nullptr);

  // LN2: attn R3 -> R0 (v_t dead)
  ln2048_bf16_kernel<<<8192, 256, 0, stream>>>(R3, ln2_w, ln2_b, R0);

  // x2b = bf16(x + out_ln @ w_out.T + b_out) -> R1 (q_raw dead)
  cast_kernel<<<2048, 256, 0, stream>>>(w_out, wbuf, 524288);
  gemmA128_kernel<0, 1, 0><<<dim3(4, 64, 1), 512, 0, stream>>>(
      R0, 2048, 0, wbuf, 2048, 0, x2b, 1024, 0, 2048, b_out, x);

  // h2 = LN(x2b) -> R2 (scores dead)
  ln1024b_kernel<<<8192, 256, 0, stream>>>(x2b, ln1_w, ln1_b, R2);

  // m1 = gelu(h2 @ w1.T + b1) -> R3+R4 span (attn, q_conv dead)
  cast_kernel<<<4096, 256, 0, stream>>>(w1, wbuf, 1048576);
  gemm256_kernel<EPI_GELU><<<dim3(16, 32, 1), 512, 0, stream>>>(
      R2, 1024, 0, wbuf, 1024, 0, R3, 4096, 0, 1024,
      b1, nullptr, nullptr, nullptr, nullptr, nullptr, nullptr, nullptr);

  // out = x2b + m1 @ w2.T + b2
  cast_kernel<<<4096, 256, 0, stream>>>(w2, wbuf, 1048576);
  gemmA128_kernel<1, 0, 0><<<dim3(4, 64, 1), 512, 0, stream>>>(
      R3, 4096, 0, wbuf, 4096, 0, out, 1024, 0, 4096, b2, x2b);
}

// Round 18
// 644.215 us; speedup vs baseline: 1.1190x; 1.1190x over previous
//
#include <hip/hip_runtime.h>
#include <hip/hip_bf16.h>
#include <math.h>

using bf16 = __hip_bfloat16;
typedef __attribute__((ext_vector_type(8))) short bf16x8;
typedef __attribute__((ext_vector_type(4))) float f32x4;

#define DEVI __device__ __forceinline__

DEVI float b2f(bf16 v) { return __bfloat162float(v); }
DEVI bf16 f2b(float v) { return __float2bfloat16(v); }
DEVI short b2s(bf16 v) { return *reinterpret_cast<short*>(&v); }
DEVI float s2f(short s) {
  unsigned int u = ((unsigned int)(unsigned short)s) << 16;
  return __uint_as_float(u);
}
DEVI float geluf(float x) { return 0.5f * x * (1.0f + erff(x * 0.70710678118654752f)); }
DEVI float fsilu(float x) { return x / (1.0f + __expf(-x)); }  // fast-exp silu (err ~1e-6)

DEVI void load_lds16(const bf16* g, bf16* l) {
  __builtin_amdgcn_global_load_lds(
      (const __attribute__((address_space(1))) void*)g,
      (__attribute__((address_space(3))) void*)l, 16, 0, 0);
}

// ---------------- prep kernels ----------------
__global__ __launch_bounds__(256) void cast_kernel(const float* __restrict__ in,
                                                   bf16* __restrict__ out, int n4) {
  int i = blockIdx.x * 256 + threadIdx.x;
  if (i >= n4) return;
  float4 v = reinterpret_cast<const float4*>(in)[i];
  bf16 o[4] = { f2b(v.x), f2b(v.y), f2b(v.z), f2b(v.w) };
  reinterpret_cast<uint2*>(out)[i] = *reinterpret_cast<uint2*>(o);
}

// merged pmean (blocks 0-3) + wb2sum (blocks 4-515)
__global__ __launch_bounds__(256) void prep_kernel(const float* __restrict__ rel,
                                                   float* __restrict__ pm,
                                                   const float* __restrict__ wb,
                                                   float* __restrict__ wb2s) {
  const int b = blockIdx.x;
  if (b < 4) {
    int h = b * 256 + threadIdx.x;
    float s = 0.f;
    for (int m = 0; m < 1024; ++m) s += rel[m * 1024 + h];
    pm[h] = s * (1.0f / 1024.0f);
  } else {
    int e = (b - 4) * 4 + (threadIdx.x >> 6);
    int lane = threadIdx.x & 63;
    float s = 0.f;
    for (int j = lane; j < 1024; j += 64) s += wb[(long)e * 2048 + 1024 + j];
#pragma unroll
    for (int off = 32; off > 0; off >>= 1) s += __shfl_down(s, off);
    if (lane == 0) wb2s[e] = s;
  }
}

// pack conv_w [2048][3] -> 3 bf16 planes wpl[p][2048]
// MUST run after the w_qkv cast (wpl lives in wbuf's dead tail). Round-14 lesson.
__global__ __launch_bounds__(256) void convw_pack_kernel(const float* __restrict__ cw,
                                                         bf16* __restrict__ wpl) {
  int e = blockIdx.x * 256 + threadIdx.x;  // 2048
  wpl[e]        = f2b(cw[e * 3]);
  wpl[2048 + e] = f2b(cw[e * 3 + 1]);
  wpl[4096 + e] = f2b(cw[e * 3 + 2]);
}

// ---------------- LayerNorm kernels ----------------
template<bool POS>
__global__ __launch_bounds__(256) void ln1024_kernel(
    const float* __restrict__ x, const float* __restrict__ w, const float* __restrict__ b,
    bf16* __restrict__ out, const float* __restrict__ pmean, float* __restrict__ pos) {
  __shared__ float red[12];
  long row = blockIdx.x;
  int t = threadIdx.x, lane = t & 63, wid = t >> 6;
  float4 xv = reinterpret_cast<const float4*>(x + row * 1024)[t];
  float s = xv.x + xv.y + xv.z + xv.w;
  float ss = xv.x * xv.x + xv.y * xv.y + xv.z * xv.z + xv.w * xv.w;
#pragma unroll
  for (int off = 32; off > 0; off >>= 1) { s += __shfl_down(s, off); ss += __shfl_down(ss, off); }
  if (lane == 0) { red[wid] = s; red[4 + wid] = ss; }
  __syncthreads();
  s = red[0] + red[1] + red[2] + red[3];
  ss = red[4] + red[5] + red[6] + red[7];
  float mean = s * (1.0f / 1024.0f);
  float rstd = rsqrtf(ss * (1.0f / 1024.0f) - mean * mean + 1e-5f);
  float4 wv = reinterpret_cast<const float4*>(w)[t];
  float4 bv = reinterpret_cast<const float4*>(b)[t];
  float h0 = (xv.x - mean) * rstd * wv.x + bv.x;
  float h1 = (xv.y - mean) * rstd * wv.y + bv.y;
  float h2 = (xv.z - mean) * rstd * wv.z + bv.z;
  float h3 = (xv.w - mean) * rstd * wv.w + bv.w;
  bf16 o[4] = { f2b(h0), f2b(h1), f2b(h2), f2b(h3) };
  reinterpret_cast<uint2*>(out + row * 1024)[t] = *reinterpret_cast<uint2*>(o);
  if (POS) {
    float4 pv = reinterpret_cast<const float4*>(pmean)[t];
    float d = h0 * pv.x + h1 * pv.y + h2 * pv.z + h3 * pv.w;
#pragma unroll
    for (int off = 32; off > 0; off >>= 1) d += __shfl_down(d, off);
    if (lane == 0) red[8 + wid] = d;
    __syncthreads();
    if (t == 0) pos[row] = red[8] + red[9] + red[10] + red[11];
  }
}

// bf16-input variant (for h2 = LN(x2b))
__global__ __launch_bounds__(256) void ln1024b_kernel(
    const bf16* __restrict__ x, const float* __restrict__ w, const float* __restrict__ b,
    bf16* __restrict__ out) {
  __shared__ float red[8];
  long row = blockIdx.x;
  int t = threadIdx.x, lane = t & 63, wid = t >> 6;
  bf16 tv[4];
  *reinterpret_cast<uint2*>(tv) = reinterpret_cast<const uint2*>(x + row * 1024)[t];
  float v[4], s = 0.f, ss = 0.f;
#pragma unroll
  for (int j = 0; j < 4; ++j) { v[j] = b2f(tv[j]); s += v[j]; ss += v[j] * v[j]; }
#pragma unroll
  for (int off = 32; off > 0; off >>= 1) { s += __shfl_down(s, off); ss += __shfl_down(ss, off); }
  if (lane == 0) { red[wid] = s; red[4 + wid] = ss; }
  __syncthreads();
  s = red[0] + red[1] + red[2] + red[3];
  ss = red[4] + red[5] + red[6] + red[7];
  float mean = s * (1.0f / 1024.0f);
  float rstd = rsqrtf(ss * (1.0f / 1024.0f) - mean * mean + 1e-5f);
  float4 wv = reinterpret_cast<const float4*>(w)[t];
  float4 bv = reinterpret_cast<const float4*>(b)[t];
  bf16 o[4];
  o[0] = f2b((v[0] - mean) * rstd * wv.x + bv.x);
  o[1] = f2b((v[1] - mean) * rstd * wv.y + bv.y);
  o[2] = f2b((v[2] - mean) * rstd * wv.z + bv.z);
  o[3] = f2b((v[3] - mean) * rstd * wv.w + bv.w);
  reinterpret_cast<uint2*>(out + row * 1024)[t] = *reinterpret_cast<uint2*>(o);
}

__global__ __launch_bounds__(256) void ln2048_bf16_kernel(
    const bf16* __restrict__ in, const float* __restrict__ w, const float* __restrict__ b,
    bf16* __restrict__ out) {
  __shared__ float red[8];
  long row = blockIdx.x;
  int t = threadIdx.x, lane = t & 63, wid = t >> 6;
  bf16 tv[8];
  *reinterpret_cast<int4*>(tv) = reinterpret_cast<const int4*>(in + row * 2048)[t];
  float v[8], s = 0.f, ss = 0.f;
#pragma unroll
  for (int j = 0; j < 8; ++j) { v[j] = b2f(tv[j]); s += v[j]; ss += v[j] * v[j]; }
#pragma unroll
  for (int off = 32; off > 0; off >>= 1) { s += __shfl_down(s, off); ss += __shfl_down(ss, off); }
  if (lane == 0) { red[wid] = s; red[4 + wid] = ss; }
  __syncthreads();
  s = red[0] + red[1] + red[2] + red[3];
  ss = red[4] + red[5] + red[6] + red[7];
  float mean = s * (1.0f / 2048.0f);
  float rstd = rsqrtf(ss * (1.0f / 2048.0f) - mean * mean + 1e-5f);
  int base = t * 8;
  bf16 o[8];
#pragma unroll
  for (int j = 0; j < 8; ++j) o[j] = f2b((v[j] - mean) * rstd * w[base + j] + b[base + j]);
  reinterpret_cast<int4*>(out + row * 2048)[t] = *reinterpret_cast<int4*>(o);
}

// ======= tiled fused act/cross-norm + dwconv for q,k (round-12 proven) =======
#define QK_TAP(RR, WV) { \
  float qmv = s2f(qs[RR][j]), kmv = s2f(ks[RR][j]); \
  float qn = qmv * rq[RR] + 0.1f * kmv; \
  float kn = kmv * rk[RR] + 0.1f * qn; \
  accq += b2f(WV[j]) * b2f(f2b(qn)); \
  acck += b2f(WV[j]) * b2f(f2b(kn)); }

__global__ __launch_bounds__(256) void actconv_qk_kernel(
    const bf16* __restrict__ qraw, const bf16* __restrict__ kraw,
    bf16* __restrict__ qout, bf16* __restrict__ kout, const bf16* __restrict__ wpl) {
  __shared__ float red[10][2][4];
  const int t = threadIdx.x, lane = t & 63, wid = t >> 6;
  const int e0 = t * 8;
  const int bb = blockIdx.x >> 7;
  const int l0 = (blockIdx.x & 127) * 8;
  const long rowbase = (long)bb * 1024 * 2048;
  bf16x8 qs[10], ks[10];
#pragma unroll
  for (int r = 0; r < 10; ++r) {
    int dl = l0 + r - 1;
    float sq = 0.f, sk = 0.f;
    if (dl >= 0 && dl < 1024) {
      long off = rowbase + (long)dl * 2048 + e0;
      bf16 tq[8], tk[8];
      *reinterpret_cast<int4*>(tq) = *reinterpret_cast<const int4*>(qraw + off);
      *reinterpret_cast<int4*>(tk) = *reinterpret_cast<const int4*>(kraw + off);
#pragma unroll
      for (int j = 0; j < 8; ++j) {
        float qv = fsilu(b2f(tq[j])); sq += qv * qv; qs[r][j] = b2s(f2b(qv));
        float kv = fsilu(b2f(tk[j])); sk += kv * kv; ks[r][j] = b2s(f2b(kv));
      }
    } else {
      qs[r] = 0; ks[r] = 0;
    }
#pragma unroll
    for (int off = 32; off > 0; off >>= 1) { sq += __shfl_down(sq, off); sk += __shfl_down(sk, off); }
    if (lane == 0) { red[r][0][wid] = sq; red[r][1][wid] = sk; }
  }
  __syncthreads();
  float rq[10], rk[10];
#pragma unroll
  for (int r = 0; r < 10; ++r) {
    float sq = red[r][0][0] + red[r][0][1] + red[r][0][2] + red[r][0][3];
    float sk = red[r][1][0] + red[r][1][1] + red[r][1][2] + red[r][1][3];
    rq[r] = 1.0f / fmaxf(sqrtf(sq), 1e-12f);
    rk[r] = 1.0f / fmaxf(sqrtf(sk), 1e-12f);
  }
  bf16 w0[8], w1[8], w2[8];
  *reinterpret_cast<int4*>(w0) = *reinterpret_cast<const int4*>(wpl + e0);
  *reinterpret_cast<int4*>(w1) = *reinterpret_cast<const int4*>(wpl + 2048 + e0);
  *reinterpret_cast<int4*>(w2) = *reinterpret_cast<const int4*>(wpl + 4096 + e0);
#pragma unroll
  for (int rr = 1; rr <= 8; ++rr) {
    const int l = l0 + rr - 1;
    bf16 oq[8], ok[8];
#pragma unroll
    for (int j = 0; j < 8; ++j) {
      float accq = 0.f, acck = 0.f;
      QK_TAP(rr, w1);
      if (l > 0)    QK_TAP(rr - 1, w0);
      if (l < 1023) QK_TAP(rr + 1, w2);
      oq[j] = f2b(accq); ok[j] = f2b(acck);
    }
    long off = rowbase + (long)l * 2048 + e0;
    *reinterpret_cast<int4*>(qout + off) = *reinterpret_cast<int4*>(oq);
    *reinterpret_cast<int4*>(kout + off) = *reinterpret_cast<int4*>(ok);
  }
}

// ======= fused v-path: gelu + dwconv + beta-mult + transpose (round-16 proven) =======
__global__ __launch_bounds__(256) void transpose_vb_kernel(
    const bf16* __restrict__ vraw, const bf16* __restrict__ beta,
    bf16* __restrict__ vt, const bf16* __restrict__ wpl) {
  const long base = (long)blockIdx.z * 2097152;
  const int r0 = blockIdx.y * 64 + ((threadIdx.x & 63) >> 3) * 8;
  const int c0 = blockIdx.x * 256 + (threadIdx.x >> 6) * 64 + (threadIdx.x & 7) * 8;
  bf16 g[10][8];
#pragma unroll
  for (int j = 0; j < 10; ++j) {
    int r = r0 + j - 1;
    if (r >= 0 && r < 1024) {
      bf16 raw[8];
      *reinterpret_cast<int4*>(raw) =
          *reinterpret_cast<const int4*>(&vraw[base + (long)r * 2048 + c0]);
#pragma unroll
      for (int i = 0; i < 8; ++i) g[j][i] = f2b(geluf(b2f(raw[i])));
    } else {
#pragma unroll
      for (int i = 0; i < 8; ++i) g[j][i] = f2b(0.f);
    }
  }
  bf16 w0[8], w1[8], w2[8];
  *reinterpret_cast<int4*>(w0) = *reinterpret_cast<const int4*>(&wpl[c0]);
  *reinterpret_cast<int4*>(w1) = *reinterpret_cast<const int4*>(&wpl[2048 + c0]);
  *reinterpret_cast<int4*>(w2) = *reinterpret_cast<const int4*>(&wpl[4096 + c0]);
  bf16 vv[8][8];
#pragma unroll
  for (int j = 0; j < 8; ++j) {
    const int l = r0 + j;
    bf16 bt[8];
    *reinterpret_cast<int4*>(bt) =
        *reinterpret_cast<const int4*>(&beta[base + (long)l * 2048 + c0]);
#pragma unroll
    for (int i = 0; i < 8; ++i) {
      float a = b2f(w1[i]) * b2f(g[j + 1][i]);
      if (l > 0)    a += b2f(w0[i]) * b2f(g[j][i]);
      if (l < 1023) a += b2f(w2[i]) * b2f(g[j + 2][i]);
      vv[j][i] = f2b(b2f(bt[i]) * a);
    }
  }
#pragma unroll
  for (int i = 0; i < 8; ++i) {
    bf16 w[8];
#pragma unroll
    for (int j = 0; j < 8; ++j) w[j] = vv[j][i];
    *reinterpret_cast<int4*>(&vt[base + (long)(c0 + i) * 1024 + r0]) =
        *reinterpret_cast<int4*>(w);
  }
}

enum { EPI_QKV = 0, EPI_BETA = 1, EPI_BF16 = 2, EPI_SCALE = 3, EPI_RES_F32 = 4, EPI_GELU = 5 };

// ================= 256x256 8-phase NT GEMM (round-5/12 proven schedule) =================
// NOTE (round-13 lesson): do NOT hoist all fragment reads to phase top — spills.
// NOTE (round-17 lesson): do NOT merge qkv+beta into one N=8192 GEMM — L2 overflow.
#define MF(d, a, b) d = __builtin_amdgcn_mfma_f32_16x16x32_bf16(a, b, d, 0, 0, 0)
#define RD_A(S, MR, KK) \
  (*reinterpret_cast<const bf16x8*>(&smem[(S)*16384 + wm*8192 + ((MR)*16 + r16)*64 + ((((KK)*32) + kq8) ^ swz)]))
#define RD_B(S, NR, KK) \
  (*reinterpret_cast<const bf16x8*>(&smem[32768 + (S)*16384 + (wn>>1)*8192 + ((wn&1)*64 + (NR)*16 + r16)*64 + ((((KK)*32) + kq8) ^ swz)]))
#define STAGE_A1(S, H, Q, KT) \
  load_lds16(Abase + (long)((H)*128 + (Q)*64) * lda + (long)(KT)*64, \
             &smem[(S)*16384 + (H)*8192 + (Q)*4096 + wid*512])
#define STAGE_B1(S, H, Q, KT) \
  load_lds16(Bbase + (long)((H)*128 + (Q)*64) * ldb + (long)(KT)*64, \
             &smem[32768 + (S)*16384 + (H)*8192 + (Q)*4096 + wid*512])
#define STAGE_AH(S, H, KT) { STAGE_A1(S, H, 0, KT); STAGE_A1(S, H, 1, KT); }
#define STAGE_BH(S, H, KT) { STAGE_B1(S, H, 0, KT); STAGE_B1(S, H, 1, KT); }
#define BAR_A __builtin_amdgcn_s_barrier()
#define LGKM0 { asm volatile("s_waitcnt lgkmcnt(0)" ::: "memory"); __builtin_amdgcn_sched_barrier(0); }
#define VWAIT(LST) { if (LST) { asm volatile("s_waitcnt vmcnt(0)" ::: "memory"); } \
                     else     { asm volatile("s_waitcnt vmcnt(6)" ::: "memory"); } \
                     __builtin_amdgcn_sched_barrier(0); }

#define KTILE(S, ST1, ST2, ST3, ST4, W4) { \
  bf16x8 aL[4][2], aH[4][2], bL[2][2], bH[2][2]; \
  _Pragma("unroll") for (int m_ = 0; m_ < 4; ++m_) { aL[m_][0] = RD_A(S, m_, 0); aL[m_][1] = RD_A(S, m_, 1); } \
  _Pragma("unroll") for (int n_ = 0; n_ < 2; ++n_) { bL[n_][0] = RD_B(S, n_, 0); bL[n_][1] = RD_B(S, n_, 1); } \
  ST1; BAR_A; LGKM0; \
  __builtin_amdgcn_s_setprio(1); \
  _Pragma("unroll") for (int m_ = 0; m_ < 4; ++m_) _Pragma("unroll") for (int n_ = 0; n_ < 2; ++n_) { \
    MF(acc[m_][n_], aL[m_][0], bL[n_][0]); MF(acc[m_][n_], aL[m_][1], bL[n_][1]); } \
  __builtin_amdgcn_s_setprio(0); __builtin_amdgcn_s_barrier(); \
  _Pragma("unroll") for (int n_ = 0; n_ < 2; ++n_) { bH[n_][0] = RD_B(S, n_ + 2, 0); bH[n_][1] = RD_B(S, n_ + 2, 1); } \
  ST2; BAR_A; LGKM0; \
  __builtin_amdgcn_s_setprio(1); \
  _Pragma("unroll") for (int m_ = 0; m_ < 4; ++m_) _Pragma("unroll") for (int n_ = 0; n_ < 2; ++n_) { \
    MF(acc[m_][n_ + 2], aL[m_][0], bH[n_][0]); MF(acc[m_][n_ + 2], aL[m_][1], bH[n_][1]); } \
  __builtin_amdgcn_s_setprio(0); __builtin_amdgcn_s_barrier(); \
  _Pragma("unroll") for (int m_ = 0; m_ < 4; ++m_) { aH[m_][0] = RD_A(S, m_ + 4, 0); aH[m_][1] = RD_A(S, m_ + 4, 1); } \
  ST3; BAR_A; LGKM0; \
  __builtin_amdgcn_s_setprio(1); \
  _Pragma("unroll") for (int m_ = 0; m_ < 4; ++m_) _Pragma("unroll") for (int n_ = 0; n_ < 2; ++n_) { \
    MF(acc[m_ + 4][n_], aH[m_][0], bL[n_][0]); MF(acc[m_ + 4][n_], aH[m_][1], bL[n_][1]); } \
  __builtin_amdgcn_s_setprio(0); __builtin_amdgcn_s_barrier(); \
  ST4; W4; BAR_A; LGKM0; \
  __builtin_amdgcn_s_setprio(1); \
  _Pragma("unroll") for (int m_ = 0; m_ < 4; ++m_) _Pragma("unroll") for (int n_ = 0; n_ < 2; ++n_) { \
    MF(acc[m_ + 4][n_ + 2], aH[m_][0], bH[n_][0]); MF(acc[m_ + 4][n_ + 2], aH[m_][1], bH[n_][1]); } \
  __builtin_amdgcn_s_setprio(0); __builtin_amdgcn_s_barrier(); \
}

template<int EPI>
__global__ __launch_bounds__(512) void gemm256_kernel(
    const bf16* __restrict__ A, int lda, long sA,
    const bf16* __restrict__ B, int ldb, long sB,
    void* __restrict__ Cv, int ldc, long sC, int K,
    const float* __restrict__ bias, const float* __restrict__ aux_row,
    const float* __restrict__ aux_col, const bf16* __restrict__ vconv,
    const float* __restrict__ resid, const float* __restrict__ scale_ptr,
    bf16* __restrict__ p2, bf16* __restrict__ p3) {
  __shared__ bf16 smem[65536];
  const int bz = blockIdx.z;
  A += (long)bz * sA;
  B += (long)bz * sB;
  const int m0 = blockIdx.y * 256, n0 = blockIdx.x * 256;
  const int t = threadIdx.x, lane = t & 63, wid = t >> 6;
  const int wm = wid >> 2, wn = wid & 3;
  const int r16 = lane & 15, kq8 = (lane >> 4) * 8;
  const int swz = (r16 & 7) << 3;
  const int lrow = lane >> 3;
  const int cswz = ((lane & 7) ^ lrow) * 8;
  const bf16* Abase = A + (long)(m0 + wid * 8 + lrow) * lda + cswz;
  const bf16* Bbase = B + (long)(n0 + wid * 8 + lrow) * ldb + cswz;
  f32x4 acc[8][4] = {};
  const int NT = K >> 6, NIT = NT >> 1;
  STAGE_AH(0, 0, 0); STAGE_AH(0, 1, 0); STAGE_BH(0, 0, 0); STAGE_BH(0, 1, 0);
  STAGE_BH(1, 0, 1); STAGE_BH(1, 1, 1); STAGE_AH(1, 0, 1);
  asm volatile("s_waitcnt vmcnt(6)" ::: "memory");
  __builtin_amdgcn_sched_barrier(0);
  __builtin_amdgcn_s_barrier();
  for (int i = 0; i < NIT; ++i) {
    const int tb = 2 * i;
    const bool lst = (i == NIT - 1);
    KTILE(0,
      { STAGE_AH(1, 1, tb + 1); },
      { },
      { if (!lst) { STAGE_BH(0, 0, tb + 2); STAGE_BH(0, 1, tb + 2); } },
      { if (!lst) { STAGE_AH(0, 0, tb + 2); } },
      VWAIT(lst));
    KTILE(1,
      { if (!lst) { STAGE_AH(0, 1, tb + 2); } },
      { },
      { if (!lst) { STAGE_BH(1, 0, tb + 3); STAGE_BH(1, 1, tb + 3); } },
      { if (!lst) { STAGE_AH(1, 0, tb + 3); } },
      VWAIT(lst));
  }
  float scl = 1.0f;
  if (EPI == EPI_SCALE) scl = scale_ptr[0];
  const int rb = (lane >> 4) * 4;
#pragma unroll
  for (int mr = 0; mr < 8; ++mr) {
#pragma unroll
    for (int nr = 0; nr < 4; ++nr) {
#pragma unroll
      for (int r = 0; r < 4; ++r) {
        const long gm = m0 + wm * 128 + mr * 16 + rb + r;
        const int gn = n0 + wn * 64 + nr * 16 + r16;
        const long idx = (long)bz * sC + gm * (long)ldc + gn;
        float v = acc[mr][nr][r];
        if (EPI == EPI_QKV) {
          const int seg = gn >> 11, cc = gn & 2047;
          bf16* dst = (seg == 0) ? (bf16*)Cv : (seg == 1) ? p2 : p3;
          dst[gm * 2048 + cc] = f2b(v + bias[gn]);
        } else if (EPI == EPI_BETA) {
          float tt = v + bias[gn] + aux_row[gm] * aux_col[gn];
          float be = 0.9f / (1.0f + expf(-tt)) + 0.1f;
          ((bf16*)Cv)[idx] = f2b(be);   // beta itself; v-mult fused into transpose_vb
        } else if (EPI == EPI_BF16) {
          ((bf16*)Cv)[idx] = f2b(v);
        } else if (EPI == EPI_SCALE) {
          ((bf16*)Cv)[idx] = f2b(v * scl);
        } else if (EPI == EPI_RES_F32) {
          ((float*)Cv)[idx] = v + bias[gn] + resid[idx];
        } else {
          ((bf16*)Cv)[idx] = f2b(geluf(v + bias[gn]));
        }
      }
    }
  }
}

// ================= 128x256-tile pipelined NT GEMM =================
// RB: resid bf16 (else f32). WB: out bf16 (else f32). NR: no bias/resid.
#define A_RD(S, MR, KK) \
  (*reinterpret_cast<const bf16x8*>(&amem[(S)*8192 + (wm*64 + (MR)*16 + r16)*64 + ((((KK)*32) + kq8) ^ swz)]))
#define B_RD(S, NR, KK) \
  (*reinterpret_cast<const bf16x8*>(&amem[16384 + (S)*16384 + (wn*64 + (NR)*16 + r16)*64 + ((((KK)*32) + kq8) ^ swz)]))
#define A_ST(S, Q, KT) \
  load_lds16(Abase + (long)((Q)*64) * lda + (long)(KT)*64, &amem[(S)*8192 + (Q)*4096 + wid*512])
#define B_ST(S, Q, KT) \
  load_lds16(Bbase + (long)((Q)*64) * ldb + (long)(KT)*64, &amem[16384 + (S)*16384 + (Q)*4096 + wid*512])
#define STAGE_T(S, KT) { A_ST(S, 0, KT); A_ST(S, 1, KT); B_ST(S, 0, KT); B_ST(S, 1, KT); B_ST(S, 2, KT); B_ST(S, 3, KT); }

template<int RB, int WB, int NR>
__global__ __launch_bounds__(512) void gemmA128_kernel(
    const bf16* __restrict__ A, int lda, long sA,
    const bf16* __restrict__ B, int ldb, long sB,
    void* __restrict__ Cv, int ldc, long sC, int K,
    const float* __restrict__ bias, const void* __restrict__ residv) {
  __shared__ bf16 amem[49152];
  A += (long)blockIdx.z * sA;
  B += (long)blockIdx.z * sB;
  const int m0 = blockIdx.y * 128, n0 = blockIdx.x * 256;
  const int t = threadIdx.x, lane = t & 63, wid = t >> 6;
  const int wm = wid >> 2, wn = wid & 3;
  const int r16 = lane & 15, kq8 = (lane >> 4) * 8;
  const int swz = (r16 & 7) << 3;
  const int lrow = lane >> 3;
  const int cswz = ((lane & 7) ^ lrow) * 8;
  const bf16* Abase = A + (long)(m0 + wid * 8 + lrow) * lda + cswz;
  const bf16* Bbase = B + (long)(n0 + wid * 8 + lrow) * ldb + cswz;
  f32x4 acc[4][4] = {};
  const int NT = K >> 6;
  STAGE_T(0, 0); STAGE_T(1, 1);
  asm volatile("s_waitcnt vmcnt(6)" ::: "memory");
  __builtin_amdgcn_sched_barrier(0);
  __builtin_amdgcn_s_barrier();
  for (int tt = 0; tt < NT; ++tt) {
    const int S = tt & 1;
    const bool pre = (tt + 2 < NT);
    bf16x8 a[4][2], bL[2][2], bH[2][2];
#pragma unroll
    for (int m_ = 0; m_ < 4; ++m_) { a[m_][0] = A_RD(S, m_, 0); a[m_][1] = A_RD(S, m_, 1); }
#pragma unroll
    for (int n_ = 0; n_ < 2; ++n_) { bL[n_][0] = B_RD(S, n_, 0); bL[n_][1] = B_RD(S, n_, 1); }
#pragma unroll
    for (int n_ = 0; n_ < 2; ++n_) { bH[n_][0] = B_RD(S, n_ + 2, 0); bH[n_][1] = B_RD(S, n_ + 2, 1); }
    LGKM0;
    __builtin_amdgcn_s_setprio(1);
#pragma unroll
    for (int m_ = 0; m_ < 4; ++m_)
#pragma unroll
      for (int n_ = 0; n_ < 2; ++n_) {
        MF(acc[m_][n_], a[m_][0], bL[n_][0]); MF(acc[m_][n_], a[m_][1], bL[n_][1]);
      }
    __builtin_amdgcn_s_setprio(0);
    __builtin_amdgcn_s_barrier();
    __builtin_amdgcn_sched_barrier(0);
    if (pre) STAGE_T(S, tt + 2);
    __builtin_amdgcn_s_setprio(1);
#pragma unroll
    for (int m_ = 0; m_ < 4; ++m_)
#pragma unroll
      for (int n_ = 0; n_ < 2; ++n_) {
        MF(acc[m_][n_ + 2], a[m_][0], bH[n_][0]); MF(acc[m_][n_ + 2], a[m_][1], bH[n_][1]);
      }
    __builtin_amdgcn_s_setprio(0);
    if (pre) { asm volatile("s_waitcnt vmcnt(6)" ::: "memory"); }
    else     { asm volatile("s_waitcnt vmcnt(0)" ::: "memory"); }
    __builtin_amdgcn_sched_barrier(0);
    __builtin_amdgcn_s_barrier();
    __builtin_amdgcn_sched_barrier(0);
  }
  const int rb = (lane >> 4) * 4;
#pragma unroll
  for (int mr = 0; mr < 4; ++mr) {
#pragma unroll
    for (int nr = 0; nr < 4; ++nr) {
#pragma unroll
      for (int r = 0; r < 4; ++r) {
        const long gm = m0 + wm * 64 + mr * 16 + rb + r;
        const int gn = n0 + wn * 64 + nr * 16 + r16;
        const long idx = (long)blockIdx.z * sC + gm * (long)ldc + gn;
        float o = acc[mr][nr][r];
        if (!NR) {
          o += bias[gn];
          o += RB ? b2f(((const bf16*)residv)[idx]) : ((const float*)residv)[idx];
        }
        if (WB) ((bf16*)Cv)[idx] = f2b(o);
        else    ((float*)Cv)[idx] = o;
      }
    }
  }
}

// ---------------- orchestration (round-16 proven) ----------------
extern "C" void kernel_launch(void* const* d_in, const int* in_sizes, int n_in,
                              void* d_out, int out_size, void* d_ws, size_t ws_size,
                              hipStream_t stream) {
  (void)in_sizes; (void)n_in; (void)out_size;
  const float* x       = (const float*)d_in[0];
  const float* ln1_w   = (const float*)d_in[1];
  const float* ln1_b   = (const float*)d_in[2];
  const float* ln2_w   = (const float*)d_in[3];
  const float* ln2_b   = (const float*)d_in[4];
  const float* w_qkv   = (const float*)d_in[5];
  const float* b_qkv   = (const float*)d_in[6];
  const float* w_out   = (const float*)d_in[7];
  const float* b_out   = (const float*)d_in[8];
  const float* rel_pos = (const float*)d_in[9];
  const float* w_beta  = (const float*)d_in[10];
  const float* b_beta  = (const float*)d_in[11];
  const float* w1      = (const float*)d_in[12];
  const float* b1      = (const float*)d_in[13];
  const float* w2      = (const float*)d_in[14];
  const float* b2      = (const float*)d_in[15];
  const float* conv_w  = (const float*)d_in[16];
  const float* attn_sc = (const float*)d_in[17];
  float* out = (float*)d_out;

  if (ws_size < 180400128UL) return;
  char* ws = (char*)d_ws;
  bf16*  wbuf    = (bf16*)(ws + 0);
  bf16*  wpl     = (bf16*)(ws + 11534336UL);   // conv planes in wbuf dead-tail (pack AFTER w_qkv cast)
  float* pmean   = (float*)(ws + 12582912UL);
  float* wb2s    = (float*)(ws + 12587008UL);
  float* posinfo = (float*)(ws + 12595200UL);
  bf16* R0 = (bf16*)(ws + 12627968UL);   // h -> v_t -> out_ln
  bf16* R1 = (bf16*)(ws + 46182400UL);   // q_raw -> beta -> x2b
  bf16* R2 = (bf16*)(ws + 79736832UL);   // k_raw -> scores -> h2
  bf16* R3 = (bf16*)(ws + 113291264UL);  // k_conv -> attn -> m1(lo)
  bf16* R4 = (bf16*)(ws + 146845696UL);  // q_conv -> m1(hi)
  bf16* vscr = (bf16*)d_out;             // v_raw scratch (dead before final write)
  bf16* x2b = R1;

  prep_kernel<<<516, 256, 0, stream>>>(rel_pos, pmean, w_beta, wb2s);

  ln1024_kernel<true><<<8192, 256, 0, stream>>>(x, ln1_w, ln1_b, R0, pmean, posinfo);

  // qkv: q->R1, k->R2, v->vscr
  cast_kernel<<<6144, 256, 0, stream>>>(w_qkv, wbuf, 1572864);
  gemm256_kernel<EPI_QKV><<<dim3(24, 32, 1), 512, 0, stream>>>(
      R0, 1024, 0, wbuf, 1024, 0, R1, 2048, 0, 1024,
      b_qkv, nullptr, nullptr, nullptr, nullptr, nullptr, R2, vscr);

  // pack conv weights AFTER the w_qkv cast (wpl lives in its tail)
  convw_pack_kernel<<<8, 256, 0, stream>>>(conv_w, wpl);

  // fused tiled act+norm+conv: q_conv->R4, k_conv->R3 (reads raw R1,R2)
  actconv_qk_kernel<<<1024, 256, 0, stream>>>(R1, R2, R4, R3, wpl);

  // beta = sigmoid(h@Wb1.T + pos*wb2sum + b)*0.9+0.1 -> R1 (q_raw dead)
  cast_kernel<<<4096, 256, 0, stream>>>(w_beta, wbuf, 1048576);
  gemm256_kernel<EPI_BETA><<<dim3(8, 32, 1), 512, 0, stream>>>(
      R0, 1024, 0, wbuf, 2048, 0, R1, 2048, 0, 1024,
      b_beta, posinfo, wb2s, nullptr, nullptr, nullptr, nullptr, nullptr);

  // fused v-path: v_t = T(beta * conv(gelu(v_raw))) -> R0 (h dead after beta GEMM)
  transpose_vb_kernel<<<dim3(8, 16, 8), 256, 0, stream>>>(vscr, R1, R0, wpl);

  // scores[l,l'] = sum_e q_conv[l,e] k_conv[l',e] -> R2 bf16 (k_raw dead)
  gemmA128_kernel<0, 1, 1><<<dim3(4, 8, 8), 512, 0, stream>>>(
      R4, 2048, 2097152, R3, 2048, 2097152, R2, 1024, 1048576, 2048,
      nullptr, nullptr);

  // attn[l,f] = (sum_l' scores[l,l'] v_t[f,l']) * scale -> R3 (k_conv dead)
  gemm256_kernel<EPI_SCALE><<<dim3(8, 4, 8), 512, 0, stream>>>(
      R2, 1024, 1048576, R0, 1024, 2097152, R3, 2048, 2097152, 1024,
      nullptr, nullptr, nullptr, nullptr, nullptr, attn_sc, nullptr, nullptr);

  // LN2: attn R3 -> R0 (v_t dead)
  ln2048_bf16_kernel<<<8192, 256, 0, stream>>>(R3, ln2_w, ln2_b, R0);

  // x2b = bf16(x + out_ln @ w_out.T + b_out) -> R1 (beta dead)
  cast_kernel<<<2048, 256, 0, stream>>>(w_out, wbuf, 524288);
  gemmA128_kernel<0, 1, 0><<<dim3(4, 64, 1), 512, 0, stream>>>(
      R0, 2048, 0, wbuf, 2048, 0, x2b, 1024, 0, 2048, b_out, x);

  // h2 = LN(x2b) -> R2 (scores dead)
  ln1024b_kernel<<<8192, 256, 0, stream>>>(x2b, ln1_w, ln1_b, R2);

  cast_kernel<<<4096, 256, 0, stream>>>(w1, wbuf, 1048576);
  gemm256_kernel<EPI_GELU><<<dim3(16, 32, 1), 512, 0, stream>>>(
      R2, 1024, 0, wbuf, 1024, 0, R3, 4096, 0, 1024,
      b1, nullptr, nullptr, nullptr, nullptr, nullptr, nullptr, nullptr);

  cast_kernel<<<4096, 256, 0, stream>>>(w2, wbuf, 1048576);
  gemmA128_kernel<1, 0, 0><<<dim3(4, 64, 1), 512, 0, stream>>>(
      R3, 4096, 0, wbuf, 4096, 0, out, 1024, 0, 4096, b2, x2b);
}

// Round 19
// 624.602 us; speedup vs baseline: 1.1541x; 1.0314x over previous
//
#include <hip/hip_runtime.h>
#include <hip/hip_bf16.h>
#include <math.h>

using bf16 = __hip_bfloat16;
typedef __attribute__((ext_vector_type(8))) short bf16x8;
typedef __attribute__((ext_vector_type(4))) float f32x4;

#define DEVI __device__ __forceinline__

DEVI float b2f(bf16 v) { return __bfloat162float(v); }
DEVI bf16 f2b(float v) { return __float2bfloat16(v); }
DEVI short b2s(bf16 v) { return *reinterpret_cast<short*>(&v); }
DEVI float s2f(short s) {
  unsigned int u = ((unsigned int)(unsigned short)s) << 16;
  return __uint_as_float(u);
}
DEVI float fsilu(float x) { return x / (1.0f + __expf(-x)); }  // fast-exp silu (err ~1e-6)
// fast tanh-form gelu reduced to sigmoid: x*sigmoid(2y), y = 0.79788x(1+0.044715x^2).
// |err| <= ~1e-3 abs on |x|<=3 (sub-ulp vs bf16 at our scales). ~8 VALU vs erff's ~30.
DEVI float fgelu(float x) {
  float y = 0.7978845608f * x * (1.0f + 0.044715f * x * x);
  return x / (1.0f + __expf(-2.0f * y));
}

DEVI void load_lds16(const bf16* g, bf16* l) {
  __builtin_amdgcn_global_load_lds(
      (const __attribute__((address_space(1))) void*)g,
      (__attribute__((address_space(3))) void*)l, 16, 0, 0);
}

// ---------------- prep kernels ----------------
__global__ __launch_bounds__(256) void cast_kernel(const float* __restrict__ in,
                                                   bf16* __restrict__ out, int n4) {
  int i = blockIdx.x * 256 + threadIdx.x;
  if (i >= n4) return;
  float4 v = reinterpret_cast<const float4*>(in)[i];
  bf16 o[4] = { f2b(v.x), f2b(v.y), f2b(v.z), f2b(v.w) };
  reinterpret_cast<uint2*>(out)[i] = *reinterpret_cast<uint2*>(o);
}

// merged pmean (blocks 0-3) + wb2sum (blocks 4-515)
__global__ __launch_bounds__(256) void prep_kernel(const float* __restrict__ rel,
                                                   float* __restrict__ pm,
                                                   const float* __restrict__ wb,
                                                   float* __restrict__ wb2s) {
  const int b = blockIdx.x;
  if (b < 4) {
    int h = b * 256 + threadIdx.x;
    float s = 0.f;
    for (int m = 0; m < 1024; ++m) s += rel[m * 1024 + h];
    pm[h] = s * (1.0f / 1024.0f);
  } else {
    int e = (b - 4) * 4 + (threadIdx.x >> 6);
    int lane = threadIdx.x & 63;
    float s = 0.f;
    for (int j = lane; j < 1024; j += 64) s += wb[(long)e * 2048 + 1024 + j];
#pragma unroll
    for (int off = 32; off > 0; off >>= 1) s += __shfl_down(s, off);
    if (lane == 0) wb2s[e] = s;
  }
}

// pack conv_w [2048][3] -> 3 bf16 planes wpl[p][2048]
// MUST run after the w_qkv cast (wpl lives in wbuf's dead tail). Round-14 lesson.
__global__ __launch_bounds__(256) void convw_pack_kernel(const float* __restrict__ cw,
                                                         bf16* __restrict__ wpl) {
  int e = blockIdx.x * 256 + threadIdx.x;  // 2048
  wpl[e]        = f2b(cw[e * 3]);
  wpl[2048 + e] = f2b(cw[e * 3 + 1]);
  wpl[4096 + e] = f2b(cw[e * 3 + 2]);
}

// ---------------- LayerNorm kernels ----------------
template<bool POS>
__global__ __launch_bounds__(256) void ln1024_kernel(
    const float* __restrict__ x, const float* __restrict__ w, const float* __restrict__ b,
    bf16* __restrict__ out, const float* __restrict__ pmean, float* __restrict__ pos) {
  __shared__ float red[12];
  long row = blockIdx.x;
  int t = threadIdx.x, lane = t & 63, wid = t >> 6;
  float4 xv = reinterpret_cast<const float4*>(x + row * 1024)[t];
  float s = xv.x + xv.y + xv.z + xv.w;
  float ss = xv.x * xv.x + xv.y * xv.y + xv.z * xv.z + xv.w * xv.w;
#pragma unroll
  for (int off = 32; off > 0; off >>= 1) { s += __shfl_down(s, off); ss += __shfl_down(ss, off); }
  if (lane == 0) { red[wid] = s; red[4 + wid] = ss; }
  __syncthreads();
  s = red[0] + red[1] + red[2] + red[3];
  ss = red[4] + red[5] + red[6] + red[7];
  float mean = s * (1.0f / 1024.0f);
  float rstd = rsqrtf(ss * (1.0f / 1024.0f) - mean * mean + 1e-5f);
  float4 wv = reinterpret_cast<const float4*>(w)[t];
  float4 bv = reinterpret_cast<const float4*>(b)[t];
  float h0 = (xv.x - mean) * rstd * wv.x + bv.x;
  float h1 = (xv.y - mean) * rstd * wv.y + bv.y;
  float h2 = (xv.z - mean) * rstd * wv.z + bv.z;
  float h3 = (xv.w - mean) * rstd * wv.w + bv.w;
  bf16 o[4] = { f2b(h0), f2b(h1), f2b(h2), f2b(h3) };
  reinterpret_cast<uint2*>(out + row * 1024)[t] = *reinterpret_cast<uint2*>(o);
  if (POS) {
    float4 pv = reinterpret_cast<const float4*>(pmean)[t];
    float d = h0 * pv.x + h1 * pv.y + h2 * pv.z + h3 * pv.w;
#pragma unroll
    for (int off = 32; off > 0; off >>= 1) d += __shfl_down(d, off);
    if (lane == 0) red[8 + wid] = d;
    __syncthreads();
    if (t == 0) pos[row] = red[8] + red[9] + red[10] + red[11];
  }
}

// bf16-input variant (for h2 = LN(x2b))
__global__ __launch_bounds__(256) void ln1024b_kernel(
    const bf16* __restrict__ x, const float* __restrict__ w, const float* __restrict__ b,
    bf16* __restrict__ out) {
  __shared__ float red[8];
  long row = blockIdx.x;
  int t = threadIdx.x, lane = t & 63, wid = t >> 6;
  bf16 tv[4];
  *reinterpret_cast<uint2*>(tv) = reinterpret_cast<const uint2*>(x + row * 1024)[t];
  float v[4], s = 0.f, ss = 0.f;
#pragma unroll
  for (int j = 0; j < 4; ++j) { v[j] = b2f(tv[j]); s += v[j]; ss += v[j] * v[j]; }
#pragma unroll
  for (int off = 32; off > 0; off >>= 1) { s += __shfl_down(s, off); ss += __shfl_down(ss, off); }
  if (lane == 0) { red[wid] = s; red[4 + wid] = ss; }
  __syncthreads();
  s = red[0] + red[1] + red[2] + red[3];
  ss = red[4] + red[5] + red[6] + red[7];
  float mean = s * (1.0f / 1024.0f);
  float rstd = rsqrtf(ss * (1.0f / 1024.0f) - mean * mean + 1e-5f);
  float4 wv = reinterpret_cast<const float4*>(w)[t];
  float4 bv = reinterpret_cast<const float4*>(b)[t];
  bf16 o[4];
  o[0] = f2b((v[0] - mean) * rstd * wv.x + bv.x);
  o[1] = f2b((v[1] - mean) * rstd * wv.y + bv.y);
  o[2] = f2b((v[2] - mean) * rstd * wv.z + bv.z);
  o[3] = f2b((v[3] - mean) * rstd * wv.w + bv.w);
  reinterpret_cast<uint2*>(out + row * 1024)[t] = *reinterpret_cast<uint2*>(o);
}

__global__ __launch_bounds__(256) void ln2048_bf16_kernel(
    const bf16* __restrict__ in, const float* __restrict__ w, const float* __restrict__ b,
    bf16* __restrict__ out) {
  __shared__ float red[8];
  long row = blockIdx.x;
  int t = threadIdx.x, lane = t & 63, wid = t >> 6;
  bf16 tv[8];
  *reinterpret_cast<int4*>(tv) = reinterpret_cast<const int4*>(in + row * 2048)[t];
  float v[8], s = 0.f, ss = 0.f;
#pragma unroll
  for (int j = 0; j < 8; ++j) { v[j] = b2f(tv[j]); s += v[j]; ss += v[j] * v[j]; }
#pragma unroll
  for (int off = 32; off > 0; off >>= 1) { s += __shfl_down(s, off); ss += __shfl_down(ss, off); }
  if (lane == 0) { red[wid] = s; red[4 + wid] = ss; }
  __syncthreads();
  s = red[0] + red[1] + red[2] + red[3];
  ss = red[4] + red[5] + red[6] + red[7];
  float mean = s * (1.0f / 2048.0f);
  float rstd = rsqrtf(ss * (1.0f / 2048.0f) - mean * mean + 1e-5f);
  int base = t * 8;
  bf16 o[8];
#pragma unroll
  for (int j = 0; j < 8; ++j) o[j] = f2b((v[j] - mean) * rstd * w[base + j] + b[base + j]);
  reinterpret_cast<int4*>(out + row * 2048)[t] = *reinterpret_cast<int4*>(o);
}

// ======= tiled fused act/cross-norm + dwconv for q,k (round-12 proven) =======
#define QK_TAP(RR, WV) { \
  float qmv = s2f(qs[RR][j]), kmv = s2f(ks[RR][j]); \
  float qn = qmv * rq[RR] + 0.1f * kmv; \
  float kn = kmv * rk[RR] + 0.1f * qn; \
  accq += b2f(WV[j]) * b2f(f2b(qn)); \
  acck += b2f(WV[j]) * b2f(f2b(kn)); }

__global__ __launch_bounds__(256) void actconv_qk_kernel(
    const bf16* __restrict__ qraw, const bf16* __restrict__ kraw,
    bf16* __restrict__ qout, bf16* __restrict__ kout, const bf16* __restrict__ wpl) {
  __shared__ float red[10][2][4];
  const int t = threadIdx.x, lane = t & 63, wid = t >> 6;
  const int e0 = t * 8;
  const int bb = blockIdx.x >> 7;
  const int l0 = (blockIdx.x & 127) * 8;
  const long rowbase = (long)bb * 1024 * 2048;
  bf16x8 qs[10], ks[10];
#pragma unroll
  for (int r = 0; r < 10; ++r) {
    int dl = l0 + r - 1;
    float sq = 0.f, sk = 0.f;
    if (dl >= 0 && dl < 1024) {
      long off = rowbase + (long)dl * 2048 + e0;
      bf16 tq[8], tk[8];
      *reinterpret_cast<int4*>(tq) = *reinterpret_cast<const int4*>(qraw + off);
      *reinterpret_cast<int4*>(tk) = *reinterpret_cast<const int4*>(kraw + off);
#pragma unroll
      for (int j = 0; j < 8; ++j) {
        float qv = fsilu(b2f(tq[j])); sq += qv * qv; qs[r][j] = b2s(f2b(qv));
        float kv = fsilu(b2f(tk[j])); sk += kv * kv; ks[r][j] = b2s(f2b(kv));
      }
    } else {
      qs[r] = 0; ks[r] = 0;
    }
#pragma unroll
    for (int off = 32; off > 0; off >>= 1) { sq += __shfl_down(sq, off); sk += __shfl_down(sk, off); }
    if (lane == 0) { red[r][0][wid] = sq; red[r][1][wid] = sk; }
  }
  __syncthreads();
  float rq[10], rk[10];
#pragma unroll
  for (int r = 0; r < 10; ++r) {
    float sq = red[r][0][0] + red[r][0][1] + red[r][0][2] + red[r][0][3];
    float sk = red[r][1][0] + red[r][1][1] + red[r][1][2] + red[r][1][3];
    rq[r] = 1.0f / fmaxf(sqrtf(sq), 1e-12f);
    rk[r] = 1.0f / fmaxf(sqrtf(sk), 1e-12f);
  }
  bf16 w0[8], w1[8], w2[8];
  *reinterpret_cast<int4*>(w0) = *reinterpret_cast<const int4*>(wpl + e0);
  *reinterpret_cast<int4*>(w1) = *reinterpret_cast<const int4*>(wpl + 2048 + e0);
  *reinterpret_cast<int4*>(w2) = *reinterpret_cast<const int4*>(wpl + 4096 + e0);
#pragma unroll
  for (int rr = 1; rr <= 8; ++rr) {
    const int l = l0 + rr - 1;
    bf16 oq[8], ok[8];
#pragma unroll
    for (int j = 0; j < 8; ++j) {
      float accq = 0.f, acck = 0.f;
      QK_TAP(rr, w1);
      if (l > 0)    QK_TAP(rr - 1, w0);
      if (l < 1023) QK_TAP(rr + 1, w2);
      oq[j] = f2b(accq); ok[j] = f2b(acck);
    }
    long off = rowbase + (long)l * 2048 + e0;
    *reinterpret_cast<int4*>(qout + off) = *reinterpret_cast<int4*>(oq);
    *reinterpret_cast<int4*>(kout + off) = *reinterpret_cast<int4*>(ok);
  }
}

// ======= fused v-path: gelu + dwconv + beta-mult + transpose (round-16 proven) =======
// Round-19 change: fgelu (fast sigmoid-form) instead of erff-gelu (~30 -> ~8 VALU).
__global__ __launch_bounds__(256) void transpose_vb_kernel(
    const bf16* __restrict__ vraw, const bf16* __restrict__ beta,
    bf16* __restrict__ vt, const bf16* __restrict__ wpl) {
  const long base = (long)blockIdx.z * 2097152;
  const int r0 = blockIdx.y * 64 + ((threadIdx.x & 63) >> 3) * 8;
  const int c0 = blockIdx.x * 256 + (threadIdx.x >> 6) * 64 + (threadIdx.x & 7) * 8;
  bf16 g[10][8];
#pragma unroll
  for (int j = 0; j < 10; ++j) {
    int r = r0 + j - 1;
    if (r >= 0 && r < 1024) {
      bf16 raw[8];
      *reinterpret_cast<int4*>(raw) =
          *reinterpret_cast<const int4*>(&vraw[base + (long)r * 2048 + c0]);
#pragma unroll
      for (int i = 0; i < 8; ++i) g[j][i] = f2b(fgelu(b2f(raw[i])));
    } else {
#pragma unroll
      for (int i = 0; i < 8; ++i) g[j][i] = f2b(0.f);
    }
  }
  bf16 w0[8], w1[8], w2[8];
  *reinterpret_cast<int4*>(w0) = *reinterpret_cast<const int4*>(&wpl[c0]);
  *reinterpret_cast<int4*>(w1) = *reinterpret_cast<const int4*>(&wpl[2048 + c0]);
  *reinterpret_cast<int4*>(w2) = *reinterpret_cast<const int4*>(&wpl[4096 + c0]);
  bf16 vv[8][8];
#pragma unroll
  for (int j = 0; j < 8; ++j) {
    const int l = r0 + j;
    bf16 bt[8];
    *reinterpret_cast<int4*>(bt) =
        *reinterpret_cast<const int4*>(&beta[base + (long)l * 2048 + c0]);
#pragma unroll
    for (int i = 0; i < 8; ++i) {
      float a = b2f(w1[i]) * b2f(g[j + 1][i]);
      if (l > 0)    a += b2f(w0[i]) * b2f(g[j][i]);
      if (l < 1023) a += b2f(w2[i]) * b2f(g[j + 2][i]);
      vv[j][i] = f2b(b2f(bt[i]) * a);
    }
  }
#pragma unroll
  for (int i = 0; i < 8; ++i) {
    bf16 w[8];
#pragma unroll
    for (int j = 0; j < 8; ++j) w[j] = vv[j][i];
    *reinterpret_cast<int4*>(&vt[base + (long)(c0 + i) * 1024 + r0]) =
        *reinterpret_cast<int4*>(w);
  }
}

enum { EPI_QKV = 0, EPI_BETA = 1, EPI_BF16 = 2, EPI_SCALE = 3, EPI_RES_F32 = 4, EPI_GELU = 5 };

// ================= 256x256 8-phase NT GEMM (round-5/12 proven schedule) =================
// NOTE (round-13 lesson): do NOT hoist all fragment reads to phase top — spills.
// NOTE (round-17 lesson): do NOT merge qkv+beta into one N=8192 GEMM — L2 overflow.
#define MF(d, a, b) d = __builtin_amdgcn_mfma_f32_16x16x32_bf16(a, b, d, 0, 0, 0)
#define RD_A(S, MR, KK) \
  (*reinterpret_cast<const bf16x8*>(&smem[(S)*16384 + wm*8192 + ((MR)*16 + r16)*64 + ((((KK)*32) + kq8) ^ swz)]))
#define RD_B(S, NR, KK) \
  (*reinterpret_cast<const bf16x8*>(&smem[32768 + (S)*16384 + (wn>>1)*8192 + ((wn&1)*64 + (NR)*16 + r16)*64 + ((((KK)*32) + kq8) ^ swz)]))
#define STAGE_A1(S, H, Q, KT) \
  load_lds16(Abase + (long)((H)*128 + (Q)*64) * lda + (long)(KT)*64, \
             &smem[(S)*16384 + (H)*8192 + (Q)*4096 + wid*512])
#define STAGE_B1(S, H, Q, KT) \
  load_lds16(Bbase + (long)((H)*128 + (Q)*64) * ldb + (long)(KT)*64, \
             &smem[32768 + (S)*16384 + (H)*8192 + (Q)*4096 + wid*512])
#define STAGE_AH(S, H, KT) { STAGE_A1(S, H, 0, KT); STAGE_A1(S, H, 1, KT); }
#define STAGE_BH(S, H, KT) { STAGE_B1(S, H, 0, KT); STAGE_B1(S, H, 1, KT); }
#define BAR_A __builtin_amdgcn_s_barrier()
#define LGKM0 { asm volatile("s_waitcnt lgkmcnt(0)" ::: "memory"); __builtin_amdgcn_sched_barrier(0); }
#define VWAIT(LST) { if (LST) { asm volatile("s_waitcnt vmcnt(0)" ::: "memory"); } \
                     else     { asm volatile("s_waitcnt vmcnt(6)" ::: "memory"); } \
                     __builtin_amdgcn_sched_barrier(0); }

#define KTILE(S, ST1, ST2, ST3, ST4, W4) { \
  bf16x8 aL[4][2], aH[4][2], bL[2][2], bH[2][2]; \
  _Pragma("unroll") for (int m_ = 0; m_ < 4; ++m_) { aL[m_][0] = RD_A(S, m_, 0); aL[m_][1] = RD_A(S, m_, 1); } \
  _Pragma("unroll") for (int n_ = 0; n_ < 2; ++n_) { bL[n_][0] = RD_B(S, n_, 0); bL[n_][1] = RD_B(S, n_, 1); } \
  ST1; BAR_A; LGKM0; \
  __builtin_amdgcn_s_setprio(1); \
  _Pragma("unroll") for (int m_ = 0; m_ < 4; ++m_) _Pragma("unroll") for (int n_ = 0; n_ < 2; ++n_) { \
    MF(acc[m_][n_], aL[m_][0], bL[n_][0]); MF(acc[m_][n_], aL[m_][1], bL[n_][1]); } \
  __builtin_amdgcn_s_setprio(0); __builtin_amdgcn_s_barrier(); \
  _Pragma("unroll") for (int n_ = 0; n_ < 2; ++n_) { bH[n_][0] = RD_B(S, n_ + 2, 0); bH[n_][1] = RD_B(S, n_ + 2, 1); } \
  ST2; BAR_A; LGKM0; \
  __builtin_amdgcn_s_setprio(1); \
  _Pragma("unroll") for (int m_ = 0; m_ < 4; ++m_) _Pragma("unroll") for (int n_ = 0; n_ < 2; ++n_) { \
    MF(acc[m_][n_ + 2], aL[m_][0], bH[n_][0]); MF(acc[m_][n_ + 2], aL[m_][1], bH[n_][1]); } \
  __builtin_amdgcn_s_setprio(0); __builtin_amdgcn_s_barrier(); \
  _Pragma("unroll") for (int m_ = 0; m_ < 4; ++m_) { aH[m_][0] = RD_A(S, m_ + 4, 0); aH[m_][1] = RD_A(S, m_ + 4, 1); } \
  ST3; BAR_A; LGKM0; \
  __builtin_amdgcn_s_setprio(1); \
  _Pragma("unroll") for (int m_ = 0; m_ < 4; ++m_) _Pragma("unroll") for (int n_ = 0; n_ < 2; ++n_) { \
    MF(acc[m_ + 4][n_], aH[m_][0], bL[n_][0]); MF(acc[m_ + 4][n_], aH[m_][1], bL[n_][1]); } \
  __builtin_amdgcn_s_setprio(0); __builtin_amdgcn_s_barrier(); \
  ST4; W4; BAR_A; LGKM0; \
  __builtin_amdgcn_s_setprio(1); \
  _Pragma("unroll") for (int m_ = 0; m_ < 4; ++m_) _Pragma("unroll") for (int n_ = 0; n_ < 2; ++n_) { \
    MF(acc[m_ + 4][n_ + 2], aH[m_][0], bH[n_][0]); MF(acc[m_ + 4][n_ + 2], aH[m_][1], bH[n_][1]); } \
  __builtin_amdgcn_s_setprio(0); __builtin_amdgcn_s_barrier(); \
}

template<int EPI>
__global__ __launch_bounds__(512) void gemm256_kernel(
    const bf16* __restrict__ A, int lda, long sA,
    const bf16* __restrict__ B, int ldb, long sB,
    void* __restrict__ Cv, int ldc, long sC, int K,
    const float* __restrict__ bias, const float* __restrict__ aux_row,
    const float* __restrict__ aux_col, const bf16* __restrict__ vconv,
    const float* __restrict__ resid, const float* __restrict__ scale_ptr,
    bf16* __restrict__ p2, bf16* __restrict__ p3) {
  __shared__ bf16 smem[65536];
  const int bz = blockIdx.z;
  A += (long)bz * sA;
  B += (long)bz * sB;
  const int m0 = blockIdx.y * 256, n0 = blockIdx.x * 256;
  const int t = threadIdx.x, lane = t & 63, wid = t >> 6;
  const int wm = wid >> 2, wn = wid & 3;
  const int r16 = lane & 15, kq8 = (lane >> 4) * 8;
  const int swz = (r16 & 7) << 3;
  const int lrow = lane >> 3;
  const int cswz = ((lane & 7) ^ lrow) * 8;
  const bf16* Abase = A + (long)(m0 + wid * 8 + lrow) * lda + cswz;
  const bf16* Bbase = B + (long)(n0 + wid * 8 + lrow) * ldb + cswz;
  f32x4 acc[8][4] = {};
  const int NT = K >> 6, NIT = NT >> 1;
  STAGE_AH(0, 0, 0); STAGE_AH(0, 1, 0); STAGE_BH(0, 0, 0); STAGE_BH(0, 1, 0);
  STAGE_BH(1, 0, 1); STAGE_BH(1, 1, 1); STAGE_AH(1, 0, 1);
  asm volatile("s_waitcnt vmcnt(6)" ::: "memory");
  __builtin_amdgcn_sched_barrier(0);
  __builtin_amdgcn_s_barrier();
  for (int i = 0; i < NIT; ++i) {
    const int tb = 2 * i;
    const bool lst = (i == NIT - 1);
    KTILE(0,
      { STAGE_AH(1, 1, tb + 1); },
      { },
      { if (!lst) { STAGE_BH(0, 0, tb + 2); STAGE_BH(0, 1, tb + 2); } },
      { if (!lst) { STAGE_AH(0, 0, tb + 2); } },
      VWAIT(lst));
    KTILE(1,
      { if (!lst) { STAGE_AH(0, 1, tb + 2); } },
      { },
      { if (!lst) { STAGE_BH(1, 0, tb + 3); STAGE_BH(1, 1, tb + 3); } },
      { if (!lst) { STAGE_AH(1, 0, tb + 3); } },
      VWAIT(lst));
  }
  float scl = 1.0f;
  if (EPI == EPI_SCALE) scl = scale_ptr[0];
  const int rb = (lane >> 4) * 4;
#pragma unroll
  for (int mr = 0; mr < 8; ++mr) {
#pragma unroll
    for (int nr = 0; nr < 4; ++nr) {
#pragma unroll
      for (int r = 0; r < 4; ++r) {
        const long gm = m0 + wm * 128 + mr * 16 + rb + r;
        const int gn = n0 + wn * 64 + nr * 16 + r16;
        const long idx = (long)bz * sC + gm * (long)ldc + gn;
        float v = acc[mr][nr][r];
        if (EPI == EPI_QKV) {
          const int seg = gn >> 11, cc = gn & 2047;
          bf16* dst = (seg == 0) ? (bf16*)Cv : (seg == 1) ? p2 : p3;
          dst[gm * 2048 + cc] = f2b(v + bias[gn]);
        } else if (EPI == EPI_BETA) {
          float tt = v + bias[gn] + aux_row[gm] * aux_col[gn];
          float be = 0.9f / (1.0f + expf(-tt)) + 0.1f;
          ((bf16*)Cv)[idx] = f2b(be);   // beta itself; v-mult fused into transpose_vb
        } else if (EPI == EPI_BF16) {
          ((bf16*)Cv)[idx] = f2b(v);
        } else if (EPI == EPI_SCALE) {
          ((bf16*)Cv)[idx] = f2b(v * scl);
        } else if (EPI == EPI_RES_F32) {
          ((float*)Cv)[idx] = v + bias[gn] + resid[idx];
        } else {  // EPI_GELU — fast sigmoid-form gelu (round-19)
          ((bf16*)Cv)[idx] = f2b(fgelu(v + bias[gn]));
        }
      }
    }
  }
}

// ================= 128x256-tile pipelined NT GEMM =================
// RB: resid bf16 (else f32). WB: out bf16 (else f32). NR: no bias/resid.
#define A_RD(S, MR, KK) \
  (*reinterpret_cast<const bf16x8*>(&amem[(S)*8192 + (wm*64 + (MR)*16 + r16)*64 + ((((KK)*32) + kq8) ^ swz)]))
#define B_RD(S, NR, KK) \
  (*reinterpret_cast<const bf16x8*>(&amem[16384 + (S)*16384 + (wn*64 + (NR)*16 + r16)*64 + ((((KK)*32) + kq8) ^ swz)]))
#define A_ST(S, Q, KT) \
  load_lds16(Abase + (long)((Q)*64) * lda + (long)(KT)*64, &amem[(S)*8192 + (Q)*4096 + wid*512])
#define B_ST(S, Q, KT) \
  load_lds16(Bbase + (long)((Q)*64) * ldb + (long)(KT)*64, &amem[16384 + (S)*16384 + (Q)*4096 + wid*512])
#define STAGE_T(S, KT) { A_ST(S, 0, KT); A_ST(S, 1, KT); B_ST(S, 0, KT); B_ST(S, 1, KT); B_ST(S, 2, KT); B_ST(S, 3, KT); }

template<int RB, int WB, int NR>
__global__ __launch_bounds__(512) void gemmA128_kernel(
    const bf16* __restrict__ A, int lda, long sA,
    const bf16* __restrict__ B, int ldb, long sB,
    void* __restrict__ Cv, int ldc, long sC, int K,
    const float* __restrict__ bias, const void* __restrict__ residv) {
  __shared__ bf16 amem[49152];
  A += (long)blockIdx.z * sA;
  B += (long)blockIdx.z * sB;
  const int m0 = blockIdx.y * 128, n0 = blockIdx.x * 256;
  const int t = threadIdx.x, lane = t & 63, wid = t >> 6;
  const int wm = wid >> 2, wn = wid & 3;
  const int r16 = lane & 15, kq8 = (lane >> 4) * 8;
  const int swz = (r16 & 7) << 3;
  const int lrow = lane >> 3;
  const int cswz = ((lane & 7) ^ lrow) * 8;
  const bf16* Abase = A + (long)(m0 + wid * 8 + lrow) * lda + cswz;
  const bf16* Bbase = B + (long)(n0 + wid * 8 + lrow) * ldb + cswz;
  f32x4 acc[4][4] = {};
  const int NT = K >> 6;
  STAGE_T(0, 0); STAGE_T(1, 1);
  asm volatile("s_waitcnt vmcnt(6)" ::: "memory");
  __builtin_amdgcn_sched_barrier(0);
  __builtin_amdgcn_s_barrier();
  for (int tt = 0; tt < NT; ++tt) {
    const int S = tt & 1;
    const bool pre = (tt + 2 < NT);
    bf16x8 a[4][2], bL[2][2], bH[2][2];
#pragma unroll
    for (int m_ = 0; m_ < 4; ++m_) { a[m_][0] = A_RD(S, m_, 0); a[m_][1] = A_RD(S, m_, 1); }
#pragma unroll
    for (int n_ = 0; n_ < 2; ++n_) { bL[n_][0] = B_RD(S, n_, 0); bL[n_][1] = B_RD(S, n_, 1); }
#pragma unroll
    for (int n_ = 0; n_ < 2; ++n_) { bH[n_][0] = B_RD(S, n_ + 2, 0); bH[n_][1] = B_RD(S, n_ + 2, 1); }
    LGKM0;
    __builtin_amdgcn_s_setprio(1);
#pragma unroll
    for (int m_ = 0; m_ < 4; ++m_)
#pragma unroll
      for (int n_ = 0; n_ < 2; ++n_) {
        MF(acc[m_][n_], a[m_][0], bL[n_][0]); MF(acc[m_][n_], a[m_][1], bL[n_][1]);
      }
    __builtin_amdgcn_s_setprio(0);
    __builtin_amdgcn_s_barrier();
    __builtin_amdgcn_sched_barrier(0);
    if (pre) STAGE_T(S, tt + 2);
    __builtin_amdgcn_s_setprio(1);
#pragma unroll
    for (int m_ = 0; m_ < 4; ++m_)
#pragma unroll
      for (int n_ = 0; n_ < 2; ++n_) {
        MF(acc[m_][n_ + 2], a[m_][0], bH[n_][0]); MF(acc[m_][n_ + 2], a[m_][1], bH[n_][1]);
      }
    __builtin_amdgcn_s_setprio(0);
    if (pre) { asm volatile("s_waitcnt vmcnt(6)" ::: "memory"); }
    else     { asm volatile("s_waitcnt vmcnt(0)" ::: "memory"); }
    __builtin_amdgcn_sched_barrier(0);
    __builtin_amdgcn_s_barrier();
    __builtin_amdgcn_sched_barrier(0);
  }
  const int rb = (lane >> 4) * 4;
#pragma unroll
  for (int mr = 0; mr < 4; ++mr) {
#pragma unroll
    for (int nr = 0; nr < 4; ++nr) {
#pragma unroll
      for (int r = 0; r < 4; ++r) {
        const long gm = m0 + wm * 64 + mr * 16 + rb + r;
        const int gn = n0 + wn * 64 + nr * 16 + r16;
        const long idx = (long)blockIdx.z * sC + gm * (long)ldc + gn;
        float o = acc[mr][nr][r];
        if (!NR) {
          o += bias[gn];
          o += RB ? b2f(((const bf16*)residv)[idx]) : ((const float*)residv)[idx];
        }
        if (WB) ((bf16*)Cv)[idx] = f2b(o);
        else    ((float*)Cv)[idx] = o;
      }
    }
  }
}

// ---------------- orchestration (round-16 proven) ----------------
extern "C" void kernel_launch(void* const* d_in, const int* in_sizes, int n_in,
                              void* d_out, int out_size, void* d_ws, size_t ws_size,
                              hipStream_t stream) {
  (void)in_sizes; (void)n_in; (void)out_size;
  const float* x       = (const float*)d_in[0];
  const float* ln1_w   = (const float*)d_in[1];
  const float* ln1_b   = (const float*)d_in[2];
  const float* ln2_w   = (const float*)d_in[3];
  const float* ln2_b   = (const float*)d_in[4];
  const float* w_qkv   = (const float*)d_in[5];
  const float* b_qkv   = (const float*)d_in[6];
  const float* w_out   = (const float*)d_in[7];
  const float* b_out   = (const float*)d_in[8];
  const float* rel_pos = (const float*)d_in[9];
  const float* w_beta  = (const float*)d_in[10];
  const float* b_beta  = (const float*)d_in[11];
  const float* w1      = (const float*)d_in[12];
  const float* b1      = (const float*)d_in[13];
  const float* w2      = (const float*)d_in[14];
  const float* b2      = (const float*)d_in[15];
  const float* conv_w  = (const float*)d_in[16];
  const float* attn_sc = (const float*)d_in[17];
  float* out = (float*)d_out;

  if (ws_size < 180400128UL) return;
  char* ws = (char*)d_ws;
  bf16*  wbuf    = (bf16*)(ws + 0);
  bf16*  wpl     = (bf16*)(ws + 11534336UL);   // conv planes in wbuf dead-tail (pack AFTER w_qkv cast)
  float* pmean   = (float*)(ws + 12582912UL);
  float* wb2s    = (float*)(ws + 12587008UL);
  float* posinfo = (float*)(ws + 12595200UL);
  bf16* R0 = (bf16*)(ws + 12627968UL);   // h -> v_t -> out_ln
  bf16* R1 = (bf16*)(ws + 46182400UL);   // q_raw -> beta -> x2b
  bf16* R2 = (bf16*)(ws + 79736832UL);   // k_raw -> scores -> h2
  bf16* R3 = (bf16*)(ws + 113291264UL);  // k_conv -> attn -> m1(lo)
  bf16* R4 = (bf16*)(ws + 146845696UL);  // q_conv -> m1(hi)
  bf16* vscr = (bf16*)d_out;             // v_raw scratch (dead before final write)
  bf16* x2b = R1;

  prep_kernel<<<516, 256, 0, stream>>>(rel_pos, pmean, w_beta, wb2s);

  ln1024_kernel<true><<<8192, 256, 0, stream>>>(x, ln1_w, ln1_b, R0, pmean, posinfo);

  // qkv: q->R1, k->R2, v->vscr
  cast_kernel<<<6144, 256, 0, stream>>>(w_qkv, wbuf, 1572864);
  gemm256_kernel<EPI_QKV><<<dim3(24, 32, 1), 512, 0, stream>>>(
      R0, 1024, 0, wbuf, 1024, 0, R1, 2048, 0, 1024,
      b_qkv, nullptr, nullptr, nullptr, nullptr, nullptr, R2, vscr);

  // pack conv weights AFTER the w_qkv cast (wpl lives in its tail)
  convw_pack_kernel<<<8, 256, 0, stream>>>(conv_w, wpl);

  // fused tiled act+norm+conv: q_conv->R4, k_conv->R3 (reads raw R1,R2)
  actconv_qk_kernel<<<1024, 256, 0, stream>>>(R1, R2, R4, R3, wpl);

  // beta = sigmoid(h@Wb1.T + pos*wb2sum + b)*0.9+0.1 -> R1 (q_raw dead)
  cast_kernel<<<4096, 256, 0, stream>>>(w_beta, wbuf, 1048576);
  gemm256_kernel<EPI_BETA><<<dim3(8, 32, 1), 512, 0, stream>>>(
      R0, 1024, 0, wbuf, 2048, 0, R1, 2048, 0, 1024,
      b_beta, posinfo, wb2s, nullptr, nullptr, nullptr, nullptr, nullptr);

  // fused v-path: v_t = T(beta * conv(gelu(v_raw))) -> R0 (h dead after beta GEMM)
  transpose_vb_kernel<<<dim3(8, 16, 8), 256, 0, stream>>>(vscr, R1, R0, wpl);

  // scores[l,l'] = sum_e q_conv[l,e] k_conv[l',e] -> R2 bf16 (k_raw dead)
  gemmA128_kernel<0, 1, 1><<<dim3(4, 8, 8), 512, 0, stream>>>(
      R4, 2048, 2097152, R3, 2048, 2097152, R2, 1024, 1048576, 2048,
      nullptr, nullptr);

  // attn[l,f] = (sum_l' scores[l,l'] v_t[f,l']) * scale -> R3 (k_conv dead)
  gemm256_kernel<EPI_SCALE><<<dim3(8, 4, 8), 512, 0, stream>>>(
      R2, 1024, 1048576, R0, 1024, 2097152, R3, 2048, 2097152, 1024,
      nullptr, nullptr, nullptr, nullptr, nullptr, attn_sc, nullptr, nullptr);

  // LN2: attn R3 -> R0 (v_t dead)
  ln2048_bf16_kernel<<<8192, 256, 0, stream>>>(R3, ln2_w, ln2_b, R0);

  // x2b = bf16(x + out_ln @ w_out.T + b_out) -> R1 (beta dead)
  cast_kernel<<<2048, 256, 0, stream>>>(w_out, wbuf, 524288);
  gemmA128_kernel<0, 1, 0><<<dim3(4, 64, 1), 512, 0, stream>>>(
      R0, 2048, 0, wbuf, 2048, 0, x2b, 1024, 0, 2048, b_out, x);

  // h2 = LN(x2b) -> R2 (scores dead)
  ln1024b_kernel<<<8192, 256, 0, stream>>>(x2b, ln1_w, ln1_b, R2);

  cast_kernel<<<4096, 256, 0, stream>>>(w1, wbuf, 1048576);
  gemm256_kernel<EPI_GELU><<<dim3(16, 32, 1), 512, 0, stream>>>(
      R2, 1024, 0, wbuf, 1024, 0, R3, 4096, 0, 1024,
      b1, nullptr, nullptr, nullptr, nullptr, nullptr, nullptr, nullptr);

  cast_kernel<<<4096, 256, 0, stream>>>(w2, wbuf, 1048576);
  gemmA128_kernel<1, 0, 0><<<dim3(4, 64, 1), 512, 0, stream>>>(
      R3, 4096, 0, wbuf, 4096, 0, out, 1024, 0, 4096, b2, x2b);
}

// Round 20
// 622.401 us; speedup vs baseline: 1.1582x; 1.0035x over previous
//
#include <hip/hip_runtime.h>
#include <hip/hip_bf16.h>
#include <math.h>

using bf16 = __hip_bfloat16;
typedef __attribute__((ext_vector_type(8))) short bf16x8;
typedef __attribute__((ext_vector_type(4))) float f32x4;

#define DEVI __device__ __forceinline__

DEVI float b2f(bf16 v) { return __bfloat162float(v); }
DEVI bf16 f2b(float v) { return __float2bfloat16(v); }
DEVI short b2s(bf16 v) { return *reinterpret_cast<short*>(&v); }
DEVI float s2f(short s) {
  unsigned int u = ((unsigned int)(unsigned short)s) << 16;
  return __uint_as_float(u);
}
DEVI float fsilu(float x) { return x / (1.0f + __expf(-x)); }  // fast-exp silu (err ~1e-6)
// fast tanh-form gelu reduced to sigmoid: x*sigmoid(2y), y = 0.79788x(1+0.044715x^2).
DEVI float fgelu(float x) {
  float y = 0.7978845608f * x * (1.0f + 0.044715f * x * x);
  return x / (1.0f + __expf(-2.0f * y));
}

DEVI void load_lds16(const bf16* g, bf16* l) {
  __builtin_amdgcn_global_load_lds(
      (const __attribute__((address_space(1))) void*)g,
      (__attribute__((address_space(3))) void*)l, 16, 0, 0);
}

// ---------------- prep kernels ----------------
__global__ __launch_bounds__(256) void cast_kernel(const float* __restrict__ in,
                                                   bf16* __restrict__ out, int n4) {
  int i = blockIdx.x * 256 + threadIdx.x;
  if (i >= n4) return;
  float4 v = reinterpret_cast<const float4*>(in)[i];
  bf16 o[4] = { f2b(v.x), f2b(v.y), f2b(v.z), f2b(v.w) };
  reinterpret_cast<uint2*>(out)[i] = *reinterpret_cast<uint2*>(o);
}

// merged pmean (blocks 0-3) + wb2sum (blocks 4-515)
__global__ __launch_bounds__(256) void prep_kernel(const float* __restrict__ rel,
                                                   float* __restrict__ pm,
                                                   const float* __restrict__ wb,
                                                   float* __restrict__ wb2s) {
  const int b = blockIdx.x;
  if (b < 4) {
    int h = b * 256 + threadIdx.x;
    float s = 0.f;
    for (int m = 0; m < 1024; ++m) s += rel[m * 1024 + h];
    pm[h] = s * (1.0f / 1024.0f);
  } else {
    int e = (b - 4) * 4 + (threadIdx.x >> 6);
    int lane = threadIdx.x & 63;
    float s = 0.f;
    for (int j = lane; j < 1024; j += 64) s += wb[(long)e * 2048 + 1024 + j];
#pragma unroll
    for (int off = 32; off > 0; off >>= 1) s += __shfl_down(s, off);
    if (lane == 0) wb2s[e] = s;
  }
}

// pack conv_w [2048][3] -> 3 bf16 planes wpl[p][2048]
// MUST run after the w_qkv cast (wpl lives in wbuf's dead tail). Round-14 lesson.
__global__ __launch_bounds__(256) void convw_pack_kernel(const float* __restrict__ cw,
                                                         bf16* __restrict__ wpl) {
  int e = blockIdx.x * 256 + threadIdx.x;  // 2048
  wpl[e]        = f2b(cw[e * 3]);
  wpl[2048 + e] = f2b(cw[e * 3 + 1]);
  wpl[4096 + e] = f2b(cw[e * 3 + 2]);
}

// ---------------- LayerNorm kernels ----------------
template<bool POS>
__global__ __launch_bounds__(256) void ln1024_kernel(
    const float* __restrict__ x, const float* __restrict__ w, const float* __restrict__ b,
    bf16* __restrict__ out, const float* __restrict__ pmean, float* __restrict__ pos) {
  __shared__ float red[12];
  long row = blockIdx.x;
  int t = threadIdx.x, lane = t & 63, wid = t >> 6;
  float4 xv = reinterpret_cast<const float4*>(x + row * 1024)[t];
  float s = xv.x + xv.y + xv.z + xv.w;
  float ss = xv.x * xv.x + xv.y * xv.y + xv.z * xv.z + xv.w * xv.w;
#pragma unroll
  for (int off = 32; off > 0; off >>= 1) { s += __shfl_down(s, off); ss += __shfl_down(ss, off); }
  if (lane == 0) { red[wid] = s; red[4 + wid] = ss; }
  __syncthreads();
  s = red[0] + red[1] + red[2] + red[3];
  ss = red[4] + red[5] + red[6] + red[7];
  float mean = s * (1.0f / 1024.0f);
  float rstd = rsqrtf(ss * (1.0f / 1024.0f) - mean * mean + 1e-5f);
  float4 wv = reinterpret_cast<const float4*>(w)[t];
  float4 bv = reinterpret_cast<const float4*>(b)[t];
  float h0 = (xv.x - mean) * rstd * wv.x + bv.x;
  float h1 = (xv.y - mean) * rstd * wv.y + bv.y;
  float h2 = (xv.z - mean) * rstd * wv.z + bv.z;
  float h3 = (xv.w - mean) * rstd * wv.w + bv.w;
  bf16 o[4] = { f2b(h0), f2b(h1), f2b(h2), f2b(h3) };
  reinterpret_cast<uint2*>(out + row * 1024)[t] = *reinterpret_cast<uint2*>(o);
  if (POS) {
    float4 pv = reinterpret_cast<const float4*>(pmean)[t];
    float d = h0 * pv.x + h1 * pv.y + h2 * pv.z + h3 * pv.w;
#pragma unroll
    for (int off = 32; off > 0; off >>= 1) d += __shfl_down(d, off);
    if (lane == 0) red[8 + wid] = d;
    __syncthreads();
    if (t == 0) pos[row] = red[8] + red[9] + red[10] + red[11];
  }
}

// bf16-input variant (for h2 = LN(x2b))
__global__ __launch_bounds__(256) void ln1024b_kernel(
    const bf16* __restrict__ x, const float* __restrict__ w, const float* __restrict__ b,
    bf16* __restrict__ out) {
  __shared__ float red[8];
  long row = blockIdx.x;
  int t = threadIdx.x, lane = t & 63, wid = t >> 6;
  bf16 tv[4];
  *reinterpret_cast<uint2*>(tv) = reinterpret_cast<const uint2*>(x + row * 1024)[t];
  float v[4], s = 0.f, ss = 0.f;
#pragma unroll
  for (int j = 0; j < 4; ++j) { v[j] = b2f(tv[j]); s += v[j]; ss += v[j] * v[j]; }
#pragma unroll
  for (int off = 32; off > 0; off >>= 1) { s += __shfl_down(s, off); ss += __shfl_down(ss, off); }
  if (lane == 0) { red[wid] = s; red[4 + wid] = ss; }
  __syncthreads();
  s = red[0] + red[1] + red[2] + red[3];
  ss = red[4] + red[5] + red[6] + red[7];
  float mean = s * (1.0f / 1024.0f);
  float rstd = rsqrtf(ss * (1.0f / 1024.0f) - mean * mean + 1e-5f);
  float4 wv = reinterpret_cast<const float4*>(w)[t];
  float4 bv = reinterpret_cast<const float4*>(b)[t];
  bf16 o[4];
  o[0] = f2b((v[0] - mean) * rstd * wv.x + bv.x);
  o[1] = f2b((v[1] - mean) * rstd * wv.y + bv.y);
  o[2] = f2b((v[2] - mean) * rstd * wv.z + bv.z);
  o[3] = f2b((v[3] - mean) * rstd * wv.w + bv.w);
  reinterpret_cast<uint2*>(out + row * 1024)[t] = *reinterpret_cast<uint2*>(o);
}

__global__ __launch_bounds__(256) void ln2048_bf16_kernel(
    const bf16* __restrict__ in, const float* __restrict__ w, const float* __restrict__ b,
    bf16* __restrict__ out) {
  __shared__ float red[8];
  long row = blockIdx.x;
  int t = threadIdx.x, lane = t & 63, wid = t >> 6;
  bf16 tv[8];
  *reinterpret_cast<int4*>(tv) = reinterpret_cast<const int4*>(in + row * 2048)[t];
  float v[8], s = 0.f, ss = 0.f;
#pragma unroll
  for (int j = 0; j < 8; ++j) { v[j] = b2f(tv[j]); s += v[j]; ss += v[j] * v[j]; }
#pragma unroll
  for (int off = 32; off > 0; off >>= 1) { s += __shfl_down(s, off); ss += __shfl_down(ss, off); }
  if (lane == 0) { red[wid] = s; red[4 + wid] = ss; }
  __syncthreads();
  s = red[0] + red[1] + red[2] + red[3];
  ss = red[4] + red[5] + red[6] + red[7];
  float mean = s * (1.0f / 2048.0f);
  float rstd = rsqrtf(ss * (1.0f / 2048.0f) - mean * mean + 1e-5f);
  int base = t * 8;
  bf16 o[8];
#pragma unroll
  for (int j = 0; j < 8; ++j) o[j] = f2b((v[j] - mean) * rstd * w[base + j] + b[base + j]);
  reinterpret_cast<int4*>(out + row * 2048)[t] = *reinterpret_cast<int4*>(o);
}

// ======= tiled fused act/cross-norm + dwconv for q,k (round-12 proven) =======
#define QK_TAP(RR, WV) { \
  float qmv = s2f(qs[RR][j]), kmv = s2f(ks[RR][j]); \
  float qn = qmv * rq[RR] + 0.1f * kmv; \
  float kn = kmv * rk[RR] + 0.1f * qn; \
  accq += b2f(WV[j]) * b2f(f2b(qn)); \
  acck += b2f(WV[j]) * b2f(f2b(kn)); }

__global__ __launch_bounds__(256) void actconv_qk_kernel(
    const bf16* __restrict__ qraw, const bf16* __restrict__ kraw,
    bf16* __restrict__ qout, bf16* __restrict__ kout, const bf16* __restrict__ wpl) {
  __shared__ float red[10][2][4];
  const int t = threadIdx.x, lane = t & 63, wid = t >> 6;
  const int e0 = t * 8;
  const int bb = blockIdx.x >> 7;
  const int l0 = (blockIdx.x & 127) * 8;
  const long rowbase = (long)bb * 1024 * 2048;
  bf16x8 qs[10], ks[10];
#pragma unroll
  for (int r = 0; r < 10; ++r) {
    int dl = l0 + r - 1;
    float sq = 0.f, sk = 0.f;
    if (dl >= 0 && dl < 1024) {
      long off = rowbase + (long)dl * 2048 + e0;
      bf16 tq[8], tk[8];
      *reinterpret_cast<int4*>(tq) = *reinterpret_cast<const int4*>(qraw + off);
      *reinterpret_cast<int4*>(tk) = *reinterpret_cast<const int4*>(kraw + off);
#pragma unroll
      for (int j = 0; j < 8; ++j) {
        float qv = fsilu(b2f(tq[j])); sq += qv * qv; qs[r][j] = b2s(f2b(qv));
        float kv = fsilu(b2f(tk[j])); sk += kv * kv; ks[r][j] = b2s(f2b(kv));
      }
    } else {
      qs[r] = 0; ks[r] = 0;
    }
#pragma unroll
    for (int off = 32; off > 0; off >>= 1) { sq += __shfl_down(sq, off); sk += __shfl_down(sk, off); }
    if (lane == 0) { red[r][0][wid] = sq; red[r][1][wid] = sk; }
  }
  __syncthreads();
  float rq[10], rk[10];
#pragma unroll
  for (int r = 0; r < 10; ++r) {
    float sq = red[r][0][0] + red[r][0][1] + red[r][0][2] + red[r][0][3];
    float sk = red[r][1][0] + red[r][1][1] + red[r][1][2] + red[r][1][3];
    rq[r] = 1.0f / fmaxf(sqrtf(sq), 1e-12f);
    rk[r] = 1.0f / fmaxf(sqrtf(sk), 1e-12f);
  }
  bf16 w0[8], w1[8], w2[8];
  *reinterpret_cast<int4*>(w0) = *reinterpret_cast<const int4*>(wpl + e0);
  *reinterpret_cast<int4*>(w1) = *reinterpret_cast<const int4*>(wpl + 2048 + e0);
  *reinterpret_cast<int4*>(w2) = *reinterpret_cast<const int4*>(wpl + 4096 + e0);
#pragma unroll
  for (int rr = 1; rr <= 8; ++rr) {
    const int l = l0 + rr - 1;
    bf16 oq[8], ok[8];
#pragma unroll
    for (int j = 0; j < 8; ++j) {
      float accq = 0.f, acck = 0.f;
      QK_TAP(rr, w1);
      if (l > 0)    QK_TAP(rr - 1, w0);
      if (l < 1023) QK_TAP(rr + 1, w2);
      oq[j] = f2b(accq); ok[j] = f2b(acck);
    }
    long off = rowbase + (long)l * 2048 + e0;
    *reinterpret_cast<int4*>(qout + off) = *reinterpret_cast<int4*>(oq);
    *reinterpret_cast<int4*>(kout + off) = *reinterpret_cast<int4*>(ok);
  }
}

// ======= fused v-path: gelu + dwconv + beta-mult + transpose (round-16/19 proven) =======
__global__ __launch_bounds__(256) void transpose_vb_kernel(
    const bf16* __restrict__ vraw, const bf16* __restrict__ beta,
    bf16* __restrict__ vt, const bf16* __restrict__ wpl) {
  const long base = (long)blockIdx.z * 2097152;
  const int r0 = blockIdx.y * 64 + ((threadIdx.x & 63) >> 3) * 8;
  const int c0 = blockIdx.x * 256 + (threadIdx.x >> 6) * 64 + (threadIdx.x & 7) * 8;
  bf16 g[10][8];
#pragma unroll
  for (int j = 0; j < 10; ++j) {
    int r = r0 + j - 1;
    if (r >= 0 && r < 1024) {
      bf16 raw[8];
      *reinterpret_cast<int4*>(raw) =
          *reinterpret_cast<const int4*>(&vraw[base + (long)r * 2048 + c0]);
#pragma unroll
      for (int i = 0; i < 8; ++i) g[j][i] = f2b(fgelu(b2f(raw[i])));
    } else {
#pragma unroll
      for (int i = 0; i < 8; ++i) g[j][i] = f2b(0.f);
    }
  }
  bf16 w0[8], w1[8], w2[8];
  *reinterpret_cast<int4*>(w0) = *reinterpret_cast<const int4*>(&wpl[c0]);
  *reinterpret_cast<int4*>(w1) = *reinterpret_cast<const int4*>(&wpl[2048 + c0]);
  *reinterpret_cast<int4*>(w2) = *reinterpret_cast<const int4*>(&wpl[4096 + c0]);
  bf16 vv[8][8];
#pragma unroll
  for (int j = 0; j < 8; ++j) {
    const int l = r0 + j;
    bf16 bt[8];
    *reinterpret_cast<int4*>(bt) =
        *reinterpret_cast<const int4*>(&beta[base + (long)l * 2048 + c0]);
#pragma unroll
    for (int i = 0; i < 8; ++i) {
      float a = b2f(w1[i]) * b2f(g[j + 1][i]);
      if (l > 0)    a += b2f(w0[i]) * b2f(g[j][i]);
      if (l < 1023) a += b2f(w2[i]) * b2f(g[j + 2][i]);
      vv[j][i] = f2b(b2f(bt[i]) * a);
    }
  }
#pragma unroll
  for (int i = 0; i < 8; ++i) {
    bf16 w[8];
#pragma unroll
    for (int j = 0; j < 8; ++j) w[j] = vv[j][i];
    *reinterpret_cast<int4*>(&vt[base + (long)(c0 + i) * 1024 + r0]) =
        *reinterpret_cast<int4*>(w);
  }
}

enum { EPI_QKV = 0, EPI_BETA = 1, EPI_BF16 = 2, EPI_SCALE = 3, EPI_RES_F32 = 4, EPI_GELU = 5 };

// ================= 256x256 8-phase NT GEMM (round-5/12 proven schedule) =================
// NOTE (round-13 lesson): do NOT hoist all fragment reads to phase top — spills.
// NOTE (round-17 lesson): do NOT merge qkv+beta into one N=8192 GEMM — L2 overflow.
#define MF(d, a, b) d = __builtin_amdgcn_mfma_f32_16x16x32_bf16(a, b, d, 0, 0, 0)
#define RD_A(S, MR, KK) \
  (*reinterpret_cast<const bf16x8*>(&smem[(S)*16384 + wm*8192 + ((MR)*16 + r16)*64 + ((((KK)*32) + kq8) ^ swz)]))
#define RD_B(S, NR, KK) \
  (*reinterpret_cast<const bf16x8*>(&smem[32768 + (S)*16384 + (wn>>1)*8192 + ((wn&1)*64 + (NR)*16 + r16)*64 + ((((KK)*32) + kq8) ^ swz)]))
#define STAGE_A1(S, H, Q, KT) \
  load_lds16(Abase + (long)((H)*128 + (Q)*64) * lda + (long)(KT)*64, \
             &smem[(S)*16384 + (H)*8192 + (Q)*4096 + wid*512])
#define STAGE_B1(S, H, Q, KT) \
  load_lds16(Bbase + (long)((H)*128 + (Q)*64) * ldb + (long)(KT)*64, \
             &smem[32768 + (S)*16384 + (H)*8192 + (Q)*4096 + wid*512])
#define STAGE_AH(S, H, KT) { STAGE_A1(S, H, 0, KT); STAGE_A1(S, H, 1, KT); }
#define STAGE_BH(S, H, KT) { STAGE_B1(S, H, 0, KT); STAGE_B1(S, H, 1, KT); }
#define BAR_A __builtin_amdgcn_s_barrier()
#define LGKM0 { asm volatile("s_waitcnt lgkmcnt(0)" ::: "memory"); __builtin_amdgcn_sched_barrier(0); }
#define VWAIT(LST) { if (LST) { asm volatile("s_waitcnt vmcnt(0)" ::: "memory"); } \
                     else     { asm volatile("s_waitcnt vmcnt(6)" ::: "memory"); } \
                     __builtin_amdgcn_sched_barrier(0); }

#define KTILE(S, ST1, ST2, ST3, ST4, W4) { \
  bf16x8 aL[4][2], aH[4][2], bL[2][2], bH[2][2]; \
  _Pragma("unroll") for (int m_ = 0; m_ < 4; ++m_) { aL[m_][0] = RD_A(S, m_, 0); aL[m_][1] = RD_A(S, m_, 1); } \
  _Pragma("unroll") for (int n_ = 0; n_ < 2; ++n_) { bL[n_][0] = RD_B(S, n_, 0); bL[n_][1] = RD_B(S, n_, 1); } \
  ST1; BAR_A; LGKM0; \
  __builtin_amdgcn_s_setprio(1); \
  _Pragma("unroll") for (int m_ = 0; m_ < 4; ++m_) _Pragma("unroll") for (int n_ = 0; n_ < 2; ++n_) { \
    MF(acc[m_][n_], aL[m_][0], bL[n_][0]); MF(acc[m_][n_], aL[m_][1], bL[n_][1]); } \
  __builtin_amdgcn_s_setprio(0); __builtin_amdgcn_s_barrier(); \
  _Pragma("unroll") for (int n_ = 0; n_ < 2; ++n_) { bH[n_][0] = RD_B(S, n_ + 2, 0); bH[n_][1] = RD_B(S, n_ + 2, 1); } \
  ST2; BAR_A; LGKM0; \
  __builtin_amdgcn_s_setprio(1); \
  _Pragma("unroll") for (int m_ = 0; m_ < 4; ++m_) _Pragma("unroll") for (int n_ = 0; n_ < 2; ++n_) { \
    MF(acc[m_][n_ + 2], aL[m_][0], bH[n_][0]); MF(acc[m_][n_ + 2], aL[m_][1], bH[n_][1]); } \
  __builtin_amdgcn_s_setprio(0); __builtin_amdgcn_s_barrier(); \
  _Pragma("unroll") for (int m_ = 0; m_ < 4; ++m_) { aH[m_][0] = RD_A(S, m_ + 4, 0); aH[m_][1] = RD_A(S, m_ + 4, 1); } \
  ST3; BAR_A; LGKM0; \
  __builtin_amdgcn_s_setprio(1); \
  _Pragma("unroll") for (int m_ = 0; m_ < 4; ++m_) _Pragma("unroll") for (int n_ = 0; n_ < 2; ++n_) { \
    MF(acc[m_ + 4][n_], aH[m_][0], bL[n_][0]); MF(acc[m_ + 4][n_], aH[m_][1], bL[n_][1]); } \
  __builtin_amdgcn_s_setprio(0); __builtin_amdgcn_s_barrier(); \
  ST4; W4; BAR_A; LGKM0; \
  __builtin_amdgcn_s_setprio(1); \
  _Pragma("unroll") for (int m_ = 0; m_ < 4; ++m_) _Pragma("unroll") for (int n_ = 0; n_ < 2; ++n_) { \
    MF(acc[m_ + 4][n_ + 2], aH[m_][0], bH[n_][0]); MF(acc[m_ + 4][n_ + 2], aH[m_][1], bH[n_][1]); } \
  __builtin_amdgcn_s_setprio(0); __builtin_amdgcn_s_barrier(); \
}

template<int EPI>
__global__ __launch_bounds__(512) void gemm256_kernel(
    const bf16* __restrict__ A, int lda, long sA,
    const bf16* __restrict__ B, int ldb, long sB,
    void* __restrict__ Cv, int ldc, long sC, int K,
    const float* __restrict__ bias, const float* __restrict__ aux_row,
    const float* __restrict__ aux_col, const bf16* __restrict__ vconv,
    const float* __restrict__ resid, const float* __restrict__ scale_ptr,
    bf16* __restrict__ p2, bf16* __restrict__ p3) {
  __shared__ bf16 smem[65536];
  const int bz = blockIdx.z;
  A += (long)bz * sA;
  B += (long)bz * sB;
  const int m0 = blockIdx.y * 256, n0 = blockIdx.x * 256;
  const int t = threadIdx.x, lane = t & 63, wid = t >> 6;
  const int wm = wid >> 2, wn = wid & 3;
  const int r16 = lane & 15, kq8 = (lane >> 4) * 8;
  const int swz = (r16 & 7) << 3;
  const int lrow = lane >> 3;
  const int cswz = ((lane & 7) ^ lrow) * 8;
  const bf16* Abase = A + (long)(m0 + wid * 8 + lrow) * lda + cswz;
  const bf16* Bbase = B + (long)(n0 + wid * 8 + lrow) * ldb + cswz;
  f32x4 acc[8][4] = {};
  const int NT = K >> 6, NIT = NT >> 1;
  STAGE_AH(0, 0, 0); STAGE_AH(0, 1, 0); STAGE_BH(0, 0, 0); STAGE_BH(0, 1, 0);
  STAGE_BH(1, 0, 1); STAGE_BH(1, 1, 1); STAGE_AH(1, 0, 1);
  asm volatile("s_waitcnt vmcnt(6)" ::: "memory");
  __builtin_amdgcn_sched_barrier(0);
  __builtin_amdgcn_s_barrier();
  for (int i = 0; i < NIT; ++i) {
    const int tb = 2 * i;
    const bool lst = (i == NIT - 1);
    KTILE(0,
      { STAGE_AH(1, 1, tb + 1); },
      { },
      { if (!lst) { STAGE_BH(0, 0, tb + 2); STAGE_BH(0, 1, tb + 2); } },
      { if (!lst) { STAGE_AH(0, 0, tb + 2); } },
      VWAIT(lst));
    KTILE(1,
      { if (!lst) { STAGE_AH(0, 1, tb + 2); } },
      { },
      { if (!lst) { STAGE_BH(1, 0, tb + 3); STAGE_BH(1, 1, tb + 3); } },
      { if (!lst) { STAGE_AH(1, 0, tb + 3); } },
      VWAIT(lst));
  }
  float scl = 1.0f;
  if (EPI == EPI_SCALE) scl = scale_ptr[0];
  const int rb = (lane >> 4) * 4;
#pragma unroll
  for (int mr = 0; mr < 8; ++mr) {
#pragma unroll
    for (int nr = 0; nr < 4; ++nr) {
#pragma unroll
      for (int r = 0; r < 4; ++r) {
        const long gm = m0 + wm * 128 + mr * 16 + rb + r;
        const int gn = n0 + wn * 64 + nr * 16 + r16;
        const long idx = (long)bz * sC + gm * (long)ldc + gn;
        float v = acc[mr][nr][r];
        if (EPI == EPI_QKV) {
          const int seg = gn >> 11, cc = gn & 2047;
          bf16* dst = (seg == 0) ? (bf16*)Cv : (seg == 1) ? p2 : p3;
          dst[gm * 2048 + cc] = f2b(v + bias[gn]);
        } else if (EPI == EPI_BETA) {
          // round-20: __expf sigmoid (err ~1e-7 abs on beta in [0.1,1])
          float tt = v + bias[gn] + aux_row[gm] * aux_col[gn];
          float be = 0.9f / (1.0f + __expf(-tt)) + 0.1f;
          ((bf16*)Cv)[idx] = f2b(be);   // beta itself; v-mult fused into transpose_vb
        } else if (EPI == EPI_BF16) {
          ((bf16*)Cv)[idx] = f2b(v);
        } else if (EPI == EPI_SCALE) {
          ((bf16*)Cv)[idx] = f2b(v * scl);
        } else if (EPI == EPI_RES_F32) {
          ((float*)Cv)[idx] = v + bias[gn] + resid[idx];
        } else {  // EPI_GELU — fast sigmoid-form gelu (round-19)
          ((bf16*)Cv)[idx] = f2b(fgelu(v + bias[gn]));
        }
      }
    }
  }
}

// ================= 128x256-tile pipelined NT GEMM =================
// RB: resid bf16 (else f32). WB: out bf16 (else f32). NR: no bias/resid.
#define A_RD(S, MR, KK) \
  (*reinterpret_cast<const bf16x8*>(&amem[(S)*8192 + (wm*64 + (MR)*16 + r16)*64 + ((((KK)*32) + kq8) ^ swz)]))
#define B_RD(S, NR, KK) \
  (*reinterpret_cast<const bf16x8*>(&amem[16384 + (S)*16384 + (wn*64 + (NR)*16 + r16)*64 + ((((KK)*32) + kq8) ^ swz)]))
#define A_ST(S, Q, KT) \
  load_lds16(Abase + (long)((Q)*64) * lda + (long)(KT)*64, &amem[(S)*8192 + (Q)*4096 + wid*512])
#define B_ST(S, Q, KT) \
  load_lds16(Bbase + (long)((Q)*64) * ldb + (long)(KT)*64, &amem[16384 + (S)*16384 + (Q)*4096 + wid*512])
#define STAGE_T(S, KT) { A_ST(S, 0, KT); A_ST(S, 1, KT); B_ST(S, 0, KT); B_ST(S, 1, KT); B_ST(S, 2, KT); B_ST(S, 3, KT); }

template<int RB, int WB, int NR>
__global__ __launch_bounds__(512) void gemmA128_kernel(
    const bf16* __restrict__ A, int lda, long sA,
    const bf16* __restrict__ B, int ldb, long sB,
    void* __restrict__ Cv, int ldc, long sC, int K,
    const float* __restrict__ bias, const void* __restrict__ residv) {
  __shared__ bf16 amem[49152];
  A += (long)blockIdx.z * sA;
  B += (long)blockIdx.z * sB;
  const int m0 = blockIdx.y * 128, n0 = blockIdx.x * 256;
  const int t = threadIdx.x, lane = t & 63, wid = t >> 6;
  const int wm = wid >> 2, wn = wid & 3;
  const int r16 = lane & 15, kq8 = (lane >> 4) * 8;
  const int swz = (r16 & 7) << 3;
  const int lrow = lane >> 3;
  const int cswz = ((lane & 7) ^ lrow) * 8;
  const bf16* Abase = A + (long)(m0 + wid * 8 + lrow) * lda + cswz;
  const bf16* Bbase = B + (long)(n0 + wid * 8 + lrow) * ldb + cswz;
  f32x4 acc[4][4] = {};
  const int NT = K >> 6;
  STAGE_T(0, 0); STAGE_T(1, 1);
  asm volatile("s_waitcnt vmcnt(6)" ::: "memory");
  __builtin_amdgcn_sched_barrier(0);
  __builtin_amdgcn_s_barrier();
  for (int tt = 0; tt < NT; ++tt) {
    const int S = tt & 1;
    const bool pre = (tt + 2 < NT);
    bf16x8 a[4][2], bL[2][2], bH[2][2];
#pragma unroll
    for (int m_ = 0; m_ < 4; ++m_) { a[m_][0] = A_RD(S, m_, 0); a[m_][1] = A_RD(S, m_, 1); }
#pragma unroll
    for (int n_ = 0; n_ < 2; ++n_) { bL[n_][0] = B_RD(S, n_, 0); bL[n_][1] = B_RD(S, n_, 1); }
#pragma unroll
    for (int n_ = 0; n_ < 2; ++n_) { bH[n_][0] = B_RD(S, n_ + 2, 0); bH[n_][1] = B_RD(S, n_ + 2, 1); }
    LGKM0;
    __builtin_amdgcn_s_setprio(1);
#pragma unroll
    for (int m_ = 0; m_ < 4; ++m_)
#pragma unroll
      for (int n_ = 0; n_ < 2; ++n_) {
        MF(acc[m_][n_], a[m_][0], bL[n_][0]); MF(acc[m_][n_], a[m_][1], bL[n_][1]);
      }
    __builtin_amdgcn_s_setprio(0);
    __builtin_amdgcn_s_barrier();
    __builtin_amdgcn_sched_barrier(0);
    if (pre) STAGE_T(S, tt + 2);
    __builtin_amdgcn_s_setprio(1);
#pragma unroll
    for (int m_ = 0; m_ < 4; ++m_)
#pragma unroll
      for (int n_ = 0; n_ < 2; ++n_) {
        MF(acc[m_][n_ + 2], a[m_][0], bH[n_][0]); MF(acc[m_][n_ + 2], a[m_][1], bH[n_][1]);
      }
    __builtin_amdgcn_s_setprio(0);
    if (pre) { asm volatile("s_waitcnt vmcnt(6)" ::: "memory"); }
    else     { asm volatile("s_waitcnt vmcnt(0)" ::: "memory"); }
    __builtin_amdgcn_sched_barrier(0);
    __builtin_amdgcn_s_barrier();
    __builtin_amdgcn_sched_barrier(0);
  }
  const int rb = (lane >> 4) * 4;
#pragma unroll
  for (int mr = 0; mr < 4; ++mr) {
#pragma unroll
    for (int nr = 0; nr < 4; ++nr) {
#pragma unroll
      for (int r = 0; r < 4; ++r) {
        const long gm = m0 + wm * 64 + mr * 16 + rb + r;
        const int gn = n0 + wn * 64 + nr * 16 + r16;
        const long idx = (long)blockIdx.z * sC + gm * (long)ldc + gn;
        float o = acc[mr][nr][r];
        if (!NR) {
          o += bias[gn];
          o += RB ? b2f(((const bf16*)residv)[idx]) : ((const float*)residv)[idx];
        }
        if (WB) ((bf16*)Cv)[idx] = f2b(o);
        else    ((float*)Cv)[idx] = o;
      }
    }
  }
}

// ---------------- orchestration (round-16 proven) ----------------
extern "C" void kernel_launch(void* const* d_in, const int* in_sizes, int n_in,
                              void* d_out, int out_size, void* d_ws, size_t ws_size,
                              hipStream_t stream) {
  (void)in_sizes; (void)n_in; (void)out_size;
  const float* x       = (const float*)d_in[0];
  const float* ln1_w   = (const float*)d_in[1];
  const float* ln1_b   = (const float*)d_in[2];
  const float* ln2_w   = (const float*)d_in[3];
  const float* ln2_b   = (const float*)d_in[4];
  const float* w_qkv   = (const float*)d_in[5];
  const float* b_qkv   = (const float*)d_in[6];
  const float* w_out   = (const float*)d_in[7];
  const float* b_out   = (const float*)d_in[8];
  const float* rel_pos = (const float*)d_in[9];
  const float* w_beta  = (const float*)d_in[10];
  const float* b_beta  = (const float*)d_in[11];
  const float* w1      = (const float*)d_in[12];
  const float* b1      = (const float*)d_in[13];
  const float* w2      = (const float*)d_in[14];
  const float* b2      = (const float*)d_in[15];
  const float* conv_w  = (const float*)d_in[16];
  const float* attn_sc = (const float*)d_in[17];
  float* out = (float*)d_out;

  if (ws_size < 180400128UL) return;
  char* ws = (char*)d_ws;
  bf16*  wbuf    = (bf16*)(ws + 0);
  bf16*  wpl     = (bf16*)(ws + 11534336UL);   // conv planes in wbuf dead-tail (pack AFTER w_qkv cast)
  float* pmean   = (float*)(ws + 12582912UL);
  float* wb2s    = (float*)(ws + 12587008UL);
  float* posinfo = (float*)(ws + 12595200UL);
  bf16* R0 = (bf16*)(ws + 12627968UL);   // h -> v_t -> out_ln
  bf16* R1 = (bf16*)(ws + 46182400UL);   // q_raw -> beta -> x2b
  bf16* R2 = (bf16*)(ws + 79736832UL);   // k_raw -> scores -> h2
  bf16* R3 = (bf16*)(ws + 113291264UL);  // k_conv -> attn -> m1(lo)
  bf16* R4 = (bf16*)(ws + 146845696UL);  // q_conv -> m1(hi)
  bf16* vscr = (bf16*)d_out;             // v_raw scratch (dead before final write)
  bf16* x2b = R1;

  prep_kernel<<<516, 256, 0, stream>>>(rel_pos, pmean, w_beta, wb2s);

  ln1024_kernel<true><<<8192, 256, 0, stream>>>(x, ln1_w, ln1_b, R0, pmean, posinfo);

  // qkv: q->R1, k->R2, v->vscr
  cast_kernel<<<6144, 256, 0, stream>>>(w_qkv, wbuf, 1572864);
  gemm256_kernel<EPI_QKV><<<dim3(24, 32, 1), 512, 0, stream>>>(
      R0, 1024, 0, wbuf, 1024, 0, R1, 2048, 0, 1024,
      b_qkv, nullptr, nullptr, nullptr, nullptr, nullptr, R2, vscr);

  // pack conv weights AFTER the w_qkv cast (wpl lives in its tail)
  convw_pack_kernel<<<8, 256, 0, stream>>>(conv_w, wpl);

  // fused tiled act+norm+conv: q_conv->R4, k_conv->R3 (reads raw R1,R2)
  actconv_qk_kernel<<<1024, 256, 0, stream>>>(R1, R2, R4, R3, wpl);

  // beta = sigmoid(h@Wb1.T + pos*wb2sum + b)*0.9+0.1 -> R1 (q_raw dead)
  cast_kernel<<<4096, 256, 0, stream>>>(w_beta, wbuf, 1048576);
  gemm256_kernel<EPI_BETA><<<dim3(8, 32, 1), 512, 0, stream>>>(
      R0, 1024, 0, wbuf, 2048, 0, R1, 2048, 0, 1024,
      b_beta, posinfo, wb2s, nullptr, nullptr, nullptr, nullptr, nullptr);

  // fused v-path: v_t = T(beta * conv(gelu(v_raw))) -> R0 (h dead after beta GEMM)
  transpose_vb_kernel<<<dim3(8, 16, 8), 256, 0, stream>>>(vscr, R1, R0, wpl);

  // scores[l,l'] = sum_e q_conv[l,e] k_conv[l',e] -> R2 bf16 (k_raw dead)
  gemmA128_kernel<0, 1, 1><<<dim3(4, 8, 8), 512, 0, stream>>>(
      R4, 2048, 2097152, R3, 2048, 2097152, R2, 1024, 1048576, 2048,
      nullptr, nullptr);

  // attn[l,f] = (sum_l' scores[l,l'] v_t[f,l']) * scale -> R3 (k_conv dead)
  gemm256_kernel<EPI_SCALE><<<dim3(8, 4, 8), 512, 0, stream>>>(
      R2, 1024, 1048576, R0, 1024, 2097152, R3, 2048, 2097152, 1024,
      nullptr, nullptr, nullptr, nullptr, nullptr, attn_sc, nullptr, nullptr);

  // LN2: attn R3 -> R0 (v_t dead)
  ln2048_bf16_kernel<<<8192, 256, 0, stream>>>(R3, ln2_w, ln2_b, R0);

  // x2b = bf16(x + out_ln @ w_out.T + b_out) -> R1 (beta dead)
  cast_kernel<<<2048, 256, 0, stream>>>(w_out, wbuf, 524288);
  gemmA128_kernel<0, 1, 0><<<dim3(4, 64, 1), 512, 0, stream>>>(
      R0, 2048, 0, wbuf, 2048, 0, x2b, 1024, 0, 2048, b_out, x);

  // h2 = LN(x2b) -> R2 (scores dead)
  ln1024b_kernel<<<8192, 256, 0, stream>>>(x2b, ln1_w, ln1_b, R2);

  cast_kernel<<<4096, 256, 0, stream>>>(w1, wbuf, 1048576);
  gemm256_kernel<EPI_GELU><<<dim3(16, 32, 1), 512, 0, stream>>>(
      R2, 1024, 0, wbuf, 1024, 0, R3, 4096, 0, 1024,
      b1, nullptr, nullptr, nullptr, nullptr, nullptr, nullptr, nullptr);

  cast_kernel<<<4096, 256, 0, stream>>>(w2, wbuf, 1048576);
  gemmA128_kernel<1, 0, 0><<<dim3(4, 64, 1), 512, 0, stream>>>(
      R3, 4096, 0, wbuf, 4096, 0, out, 1024, 0, 4096, b2, x2b);
}